// Round 1
// baseline (1276.648 us; speedup 1.0000x reference)
//
#include <hip/hip_runtime.h>

#define F_IN 256
#define H1 128
#define H2 32
#define BN_EPS 1e-5f

// ---------------------------------------------------------------------------
// edge_index dtype detection: if the buffer is int64 (little-endian, values
// < 2^31), every odd int32 word (the high halves) is 0. With real int32 data
// those slots hold random node ids in [0, 1e5) -> essentially never all zero.
// ---------------------------------------------------------------------------
__global__ void detect_k(const int* __restrict__ eb, int* __restrict__ flag) {
    __shared__ int nz;
    if (threadIdx.x == 0) nz = 0;
    __syncthreads();
    if (eb[2 * threadIdx.x + 1] != 0) atomicAdd(&nz, 1);
    __syncthreads();
    if (threadIdx.x == 0) flag[0] = (nz == 0) ? 1 : 0;
}

__device__ __forceinline__ int clampN(int v, int N) {
    return v < 0 ? 0 : (v >= N ? N - 1 : v);
}

// histogram of in-degrees (dst)
__global__ void hist_k(const int* __restrict__ eb, const int* __restrict__ flag,
                       int E, int N, int* __restrict__ cnt) {
    const int is64 = flag[0];
    const int stride = gridDim.x * blockDim.x;
    for (int e = blockIdx.x * blockDim.x + threadIdx.x; e < E; e += stride) {
        int d = is64 ? eb[2 * (E + e)] : eb[E + e];
        d = clampN(d, N);
        atomicAdd(&cnt[d], 1);
    }
}

// block-wise inclusive scan (Hillis-Steele, 1024/block)
__global__ void scan1_k(const int* __restrict__ cnt, int N,
                        int* __restrict__ incl, int* __restrict__ bsum) {
    __shared__ int sm[1024];
    const int tid = threadIdx.x;
    const int i = blockIdx.x * 1024 + tid;
    sm[tid] = (i < N) ? cnt[i] : 0;
    __syncthreads();
    for (int off = 1; off < 1024; off <<= 1) {
        int t = (tid >= off) ? sm[tid - off] : 0;
        __syncthreads();
        sm[tid] += t;
        __syncthreads();
    }
    if (i < N) incl[i] = sm[tid];
    if (tid == 1023) bsum[blockIdx.x] = sm[1023];
}

__global__ void scan2_k(int* __restrict__ bsum, int nb) {
    if (blockIdx.x == 0 && threadIdx.x == 0) {
        int acc = 0;
        for (int i = 0; i < nb; ++i) { int v = bsum[i]; bsum[i] = acc; acc += v; }
    }
}

__global__ void scan3_k(const int* __restrict__ incl, const int* __restrict__ bsum,
                        int N, int* __restrict__ row_start) {
    const int i = blockIdx.x * 1024 + threadIdx.x;
    if (i < N) row_start[i + 1] = incl[i] + bsum[blockIdx.x];
    if (i == 0) row_start[0] = 0;
}

// scatter edges into CSR (order within a bucket nondeterministic; f32-sum
// drift is ~1e-6, far under threshold)
__global__ void scatter_k(const int* __restrict__ eb, const int* __restrict__ flag,
                          int E, int N, const int* __restrict__ row_start,
                          int* __restrict__ cursor, int* __restrict__ esrc) {
    const int is64 = flag[0];
    const int stride = gridDim.x * blockDim.x;
    for (int e = blockIdx.x * blockDim.x + threadIdx.x; e < E; e += stride) {
        int s = is64 ? eb[2 * e] : eb[e];
        int d = is64 ? eb[2 * (E + e)] : eb[E + e];
        s = clampN(s, N);
        d = clampN(d, N);
        int pos = row_start[d] + atomicAdd(&cursor[d], 1);
        esrc[pos] = s;
    }
}

// ---------------------------------------------------------------------------
// aggregation: out[i] = X[i] + sum_{j in N(i)} X[j]
// one wave (64 lanes) per dst node; F=256 -> float4/lane, F=128 -> float2/lane
// neighbor loop unrolled x4 so 4 gathers are in flight per wave (latency).
// ---------------------------------------------------------------------------
__global__ void agg_f256_k(const float* __restrict__ X, const int* __restrict__ row_start,
                           const int* __restrict__ esrc, float* __restrict__ out, int N) {
    const int wid = (blockIdx.x << 2) | (threadIdx.x >> 6);
    const int lane = threadIdx.x & 63;
    if (wid >= N) return;
    const float4* X4 = (const float4*)X;
    float4* O4 = (float4*)out;
    float4 acc = X4[wid * 64 + lane];
    int p = row_start[wid];
    const int pe = row_start[wid + 1];
    for (; p + 3 < pe; p += 4) {
        int s0 = esrc[p], s1 = esrc[p + 1], s2 = esrc[p + 2], s3 = esrc[p + 3];
        float4 v0 = X4[s0 * 64 + lane];
        float4 v1 = X4[s1 * 64 + lane];
        float4 v2 = X4[s2 * 64 + lane];
        float4 v3 = X4[s3 * 64 + lane];
        acc.x += (v0.x + v1.x) + (v2.x + v3.x);
        acc.y += (v0.y + v1.y) + (v2.y + v3.y);
        acc.z += (v0.z + v1.z) + (v2.z + v3.z);
        acc.w += (v0.w + v1.w) + (v2.w + v3.w);
    }
    for (; p < pe; ++p) {
        float4 v = X4[esrc[p] * 64 + lane];
        acc.x += v.x; acc.y += v.y; acc.z += v.z; acc.w += v.w;
    }
    O4[wid * 64 + lane] = acc;
}

__global__ void agg_f128_k(const float* __restrict__ X, const int* __restrict__ row_start,
                           const int* __restrict__ esrc, float* __restrict__ out, int N) {
    const int wid = (blockIdx.x << 2) | (threadIdx.x >> 6);
    const int lane = threadIdx.x & 63;
    if (wid >= N) return;
    const float2* X2 = (const float2*)X;
    float2* O2 = (float2*)out;
    float2 acc = X2[wid * 64 + lane];
    int p = row_start[wid];
    const int pe = row_start[wid + 1];
    for (; p + 3 < pe; p += 4) {
        int s0 = esrc[p], s1 = esrc[p + 1], s2 = esrc[p + 2], s3 = esrc[p + 3];
        float2 v0 = X2[s0 * 64 + lane];
        float2 v1 = X2[s1 * 64 + lane];
        float2 v2 = X2[s2 * 64 + lane];
        float2 v3 = X2[s3 * 64 + lane];
        acc.x += (v0.x + v1.x) + (v2.x + v3.x);
        acc.y += (v0.y + v1.y) + (v2.y + v3.y);
    }
    for (; p < pe; ++p) {
        float2 v = X2[esrc[p] * 64 + lane];
        acc.x += v.x; acc.y += v.y;
    }
    O2[wid * 64 + lane] = acc;
}

// ---------------------------------------------------------------------------
// f32 vector-ALU GEMM: out[N,NC] = op(A[N,K] @ W[K,NC] + bias), op = relu?
// 64-row x NC-col block tile, K chunked by 32, As padded (+1) for banks.
// ---------------------------------------------------------------------------
template <int K, int NC, bool RELU>
__global__ __launch_bounds__(256) void gemm_k(const float* __restrict__ A,
                                              const float* __restrict__ W,
                                              const float* __restrict__ bias,
                                              float* __restrict__ out, int N) {
    constexpr int KB = 32;
    __shared__ float As[64][KB + 1];
    __shared__ float Bs[KB][NC];
    const int tid = threadIdx.x;
    const int row0 = blockIdx.x * 64;
    constexpr int CPT = NC / 16;  // cols per thread (8 or 2)
    const int tx = tid & 15, ty = tid >> 4;
    const int rbase = ty * 4, cbase = tx * CPT;

    float acc[4][CPT];
#pragma unroll
    for (int r = 0; r < 4; ++r)
#pragma unroll
        for (int c = 0; c < CPT; ++c) acc[r][c] = 0.f;

    for (int kc = 0; kc < K; kc += KB) {
        // A tile: 64x32 = 2048 f32, 8 per thread (2x float4)
#pragma unroll
        for (int i = 0; i < 2; ++i) {
            int idx = tid * 8 + i * 4;
            int r = idx >> 5, c = idx & 31;
            int gr = row0 + r;
            float4 v = make_float4(0.f, 0.f, 0.f, 0.f);
            if (gr < N) v = *(const float4*)&A[(size_t)gr * K + kc + c];
            As[r][c] = v.x; As[r][c + 1] = v.y; As[r][c + 2] = v.z; As[r][c + 3] = v.w;
        }
        // B tile: 32xNC
        constexpr int NF4 = (KB * NC) / (256 * 4);
#pragma unroll
        for (int i = 0; i < NF4; ++i) {
            int linear = (i * 256 + tid) * 4;
            int r = linear / NC, c = linear % NC;
            *(float4*)&Bs[r][c] = *(const float4*)&W[(size_t)(kc + r) * NC + c];
        }
        __syncthreads();
#pragma unroll
        for (int kk = 0; kk < KB; ++kk) {
            float a[4];
#pragma unroll
            for (int r = 0; r < 4; ++r) a[r] = As[rbase + r][kk];
            float b[CPT];
#pragma unroll
            for (int c = 0; c < CPT; ++c) b[c] = Bs[kk][cbase + c];
#pragma unroll
            for (int r = 0; r < 4; ++r)
#pragma unroll
                for (int c = 0; c < CPT; ++c) acc[r][c] += a[r] * b[c];
        }
        __syncthreads();
    }
#pragma unroll
    for (int r = 0; r < 4; ++r) {
        int gr = row0 + rbase + r;
        if (gr < N) {
#pragma unroll
            for (int c = 0; c < CPT; ++c) {
                float v = acc[r][c] + bias[cbase + c];
                if (RELU) v = fmaxf(v, 0.f);
                out[(size_t)gr * NC + cbase + c] = v;
            }
        }
    }
}

// ---------------------------------------------------------------------------
// BatchNorm: column sums/sumsq -> scale/shift -> fused apply + relu
// ---------------------------------------------------------------------------
template <int F>
__global__ void stats_k(const float* __restrict__ U, int N, float* __restrict__ sums) {
    constexpr int RPB = 256 / F;
    const int tid = threadIdx.x;
    const int col = tid % F;
    const int rsub = tid / F;
    float s = 0.f, q = 0.f;
    for (int r = blockIdx.x * RPB + rsub; r < N; r += gridDim.x * RPB) {
        float v = U[(size_t)r * F + col];
        s += v;
        q += v * v;
    }
    __shared__ float ls[256], lq[256];
    ls[tid] = s; lq[tid] = q;
    __syncthreads();
    if (tid < F) {
#pragma unroll
        for (int k = 1; k < RPB; ++k) { s += ls[tid + k * F]; q += lq[tid + k * F]; }
        atomicAdd(&sums[col], s);
        atomicAdd(&sums[F + col], q);
    }
}

template <int F>
__global__ void finalize_k(const float* __restrict__ sums, const float* __restrict__ g,
                           const float* __restrict__ be, int N,
                           float* __restrict__ scale, float* __restrict__ shift) {
    const int c = threadIdx.x;
    if (c < F) {
        float inv_n = 1.f / (float)N;
        float mean = sums[c] * inv_n;
        float var = sums[F + c] * inv_n - mean * mean;
        float sc = g[c] * rsqrtf(var + BN_EPS);
        scale[c] = sc;
        shift[c] = be[c] - mean * sc;
    }
}

template <int F>
__global__ void bnapply_k(const float* __restrict__ U, const float* __restrict__ scale,
                          const float* __restrict__ shift, float* __restrict__ out, int total4) {
    const float4* U4 = (const float4*)U;
    const float4* S4 = (const float4*)scale;
    const float4* H4 = (const float4*)shift;
    float4* O4 = (float4*)out;
    const int stride = gridDim.x * blockDim.x;
    for (int i = blockIdx.x * blockDim.x + threadIdx.x; i < total4; i += stride) {
        int c4 = i % (F / 4);
        float4 u = U4[i], sc = S4[c4], sh = H4[c4];
        float4 o;
        o.x = fmaxf(u.x * sc.x + sh.x, 0.f);
        o.y = fmaxf(u.y * sc.y + sh.y, 0.f);
        o.z = fmaxf(u.z * sc.z + sh.z, 0.f);
        o.w = fmaxf(u.w * sc.w + sh.w, 0.f);
        O4[i] = o;
    }
}

// ---------------------------------------------------------------------------
extern "C" void kernel_launch(void* const* d_in, const int* in_sizes, int n_in,
                              void* d_out, int out_size, void* d_ws, size_t ws_size,
                              hipStream_t stream) {
    const float* x   = (const float*)d_in[0];
    const int*   eb  = (const int*)d_in[1];
    const float* W1a = (const float*)d_in[2];
    const float* b1a = (const float*)d_in[3];
    const float* W1b = (const float*)d_in[4];
    const float* b1b = (const float*)d_in[5];
    const float* g1  = (const float*)d_in[6];
    const float* be1 = (const float*)d_in[7];
    const float* W2a = (const float*)d_in[8];
    const float* b2a = (const float*)d_in[9];
    const float* W2b = (const float*)d_in[10];
    const float* b2b = (const float*)d_in[11];
    const float* g2  = (const float*)d_in[12];
    const float* be2 = (const float*)d_in[13];
    float* out = (float*)d_out;

    const int N = in_sizes[0] / F_IN;  // 100000
    const int E = in_sizes[1] / 2;     // 3200000 (element count is dtype-invariant)

    char* w = (char*)d_ws;
    size_t off = 0;
    auto alloc = [&](size_t bytes) -> void* {
        void* p = w + off;
        off = (off + bytes + 255) & ~(size_t)255;
        return p;
    };
    float* R0 = (float*)alloc((size_t)N * F_IN * 4);  // s1 / s2 / u2
    float* R1 = (float*)alloc((size_t)N * H1 * 4);    // h1 / t1
    float* R2 = (float*)alloc((size_t)N * H1 * 4);    // u1 / h2
    int* row_start = (int*)alloc((size_t)(N + 1) * 4);
    int* cnt    = (int*)alloc((size_t)N * 4);
    int* cursor = (int*)alloc((size_t)N * 4);
    int* incl   = (int*)alloc((size_t)N * 4);
    int* esrc   = (int*)alloc((size_t)E * 4);
    int* bsum   = (int*)alloc(4096);
    int* flag   = (int*)alloc(256);
    float* sums1 = (float*)alloc(2 * H1 * 4);
    float* sc1   = (float*)alloc(H1 * 4);
    float* sh1   = (float*)alloc(H1 * 4);
    float* sums2 = (float*)alloc(2 * H2 * 4);
    float* sc2   = (float*)alloc(H2 * 4);
    float* sh2   = (float*)alloc(H2 * 4);

    hipMemsetAsync(cnt, 0, (size_t)N * 4, stream);
    hipMemsetAsync(cursor, 0, (size_t)N * 4, stream);
    hipMemsetAsync(sums1, 0, 2 * H1 * 4, stream);
    hipMemsetAsync(sums2, 0, 2 * H2 * 4, stream);

    // --- CSR build (by dst) ---
    detect_k<<<1, 128, 0, stream>>>(eb, flag);
    hist_k<<<2048, 256, 0, stream>>>(eb, flag, E, N, cnt);
    const int nb = (N + 1023) / 1024;
    scan1_k<<<nb, 1024, 0, stream>>>(cnt, N, incl, bsum);
    scan2_k<<<1, 64, 0, stream>>>(bsum, nb);
    scan3_k<<<nb, 1024, 0, stream>>>(incl, bsum, N, row_start);
    scatter_k<<<2048, 256, 0, stream>>>(eb, flag, E, N, row_start, cursor, esrc);

    // --- layer 1 ---
    agg_f256_k<<<(N + 3) / 4, 256, 0, stream>>>(x, row_start, esrc, R0, N);
    gemm_k<256, 128, true><<<(N + 63) / 64, 256, 0, stream>>>(R0, W1a, b1a, R1, N);
    gemm_k<128, 128, false><<<(N + 63) / 64, 256, 0, stream>>>(R1, W1b, b1b, R2, N);
    stats_k<128><<<512, 256, 0, stream>>>(R2, N, sums1);
    finalize_k<128><<<1, 128, 0, stream>>>(sums1, g1, be1, N, sc1, sh1);
    bnapply_k<128><<<12500, 256, 0, stream>>>(R2, sc1, sh1, R1, N * H1 / 4);

    // --- layer 2 ---
    agg_f128_k<<<(N + 3) / 4, 256, 0, stream>>>(R1, row_start, esrc, R0, N);
    gemm_k<128, 32, true><<<(N + 63) / 64, 256, 0, stream>>>(R0, W2a, b2a, R2, N);
    gemm_k<32, 32, false><<<(N + 63) / 64, 256, 0, stream>>>(R2, W2b, b2b, R0, N);
    stats_k<32><<<512, 256, 0, stream>>>(R0, N, sums2);
    finalize_k<32><<<1, 32, 0, stream>>>(sums2, g2, be2, N, sc2, sh2);
    bnapply_k<32><<<3125, 256, 0, stream>>>(R0, sc2, sh2, out, N * H2 / 4);
}

// Round 2
// 909.350 us; speedup vs baseline: 1.4039x; 1.4039x over previous
//
#include <hip/hip_runtime.h>

#define F_IN 256
#define H1 128
#define H2 32
#define BN_EPS 1e-5f

// ---------------------------------------------------------------------------
// edge_index dtype detection: if the buffer is int64 (little-endian, values
// < 2^31), every odd int32 word (the high halves) is 0.
// ---------------------------------------------------------------------------
__global__ void detect_k(const int* __restrict__ eb, int* __restrict__ flag) {
    __shared__ int nz;
    if (threadIdx.x == 0) nz = 0;
    __syncthreads();
    if (eb[2 * threadIdx.x + 1] != 0) atomicAdd(&nz, 1);
    __syncthreads();
    if (threadIdx.x == 0) flag[0] = (nz == 0) ? 1 : 0;
}

__device__ __forceinline__ int clampN(int v, int N) {
    return v < 0 ? 0 : (v >= N ? N - 1 : v);
}

__global__ void hist_k(const int* __restrict__ eb, const int* __restrict__ flag,
                       int E, int N, int* __restrict__ cnt) {
    const int is64 = flag[0];
    const int stride = gridDim.x * blockDim.x;
    for (int e = blockIdx.x * blockDim.x + threadIdx.x; e < E; e += stride) {
        int d = is64 ? eb[2 * (E + e)] : eb[E + e];
        d = clampN(d, N);
        atomicAdd(&cnt[d], 1);
    }
}

__global__ void scan1_k(const int* __restrict__ cnt, int N,
                        int* __restrict__ incl, int* __restrict__ bsum) {
    __shared__ int sm[1024];
    const int tid = threadIdx.x;
    const int i = blockIdx.x * 1024 + tid;
    sm[tid] = (i < N) ? cnt[i] : 0;
    __syncthreads();
    for (int off = 1; off < 1024; off <<= 1) {
        int t = (tid >= off) ? sm[tid - off] : 0;
        __syncthreads();
        sm[tid] += t;
        __syncthreads();
    }
    if (i < N) incl[i] = sm[tid];
    if (tid == 1023) bsum[blockIdx.x] = sm[1023];
}

__global__ void scan2_k(int* __restrict__ bsum, int nb) {
    if (blockIdx.x == 0 && threadIdx.x == 0) {
        int acc = 0;
        for (int i = 0; i < nb; ++i) { int v = bsum[i]; bsum[i] = acc; acc += v; }
    }
}

__global__ void scan3_k(const int* __restrict__ incl, const int* __restrict__ bsum,
                        int N, int* __restrict__ row_start) {
    const int i = blockIdx.x * 1024 + threadIdx.x;
    if (i < N) row_start[i + 1] = incl[i] + bsum[blockIdx.x];
    if (i == 0) row_start[0] = 0;
}

__global__ void scatter_k(const int* __restrict__ eb, const int* __restrict__ flag,
                          int E, int N, const int* __restrict__ row_start,
                          int* __restrict__ cursor, int* __restrict__ esrc) {
    const int is64 = flag[0];
    const int stride = gridDim.x * blockDim.x;
    for (int e = blockIdx.x * blockDim.x + threadIdx.x; e < E; e += stride) {
        int s = is64 ? eb[2 * e] : eb[e];
        int d = is64 ? eb[2 * (E + e)] : eb[E + e];
        s = clampN(s, N);
        d = clampN(d, N);
        int pos = row_start[d] + atomicAdd(&cursor[d], 1);
        esrc[pos] = s;
    }
}

// ---------------------------------------------------------------------------
// fused aggregation (post-linear): out[i] = relu(T[i] + sum_j T[j] + bias)
// F=128: one HALF-WAVE (32 lanes x float4 = full 512B row) per node.
// ---------------------------------------------------------------------------
__global__ void agg_f128_fused_k(const float* __restrict__ T, const int* __restrict__ row_start,
                                 const int* __restrict__ esrc, const float* __restrict__ bias,
                                 float* __restrict__ out, int N) {
    const int hw = (blockIdx.x << 3) | (threadIdx.x >> 5);  // 8 half-waves / block
    const int lane = threadIdx.x & 31;
    if (hw >= N) return;
    const float4* T4 = (const float4*)T;
    float4 acc = T4[(size_t)hw * 32 + lane];
    int p = row_start[hw];
    const int pe = row_start[hw + 1];
    for (; p + 3 < pe; p += 4) {
        int s0 = esrc[p], s1 = esrc[p + 1], s2 = esrc[p + 2], s3 = esrc[p + 3];
        float4 v0 = T4[(size_t)s0 * 32 + lane];
        float4 v1 = T4[(size_t)s1 * 32 + lane];
        float4 v2 = T4[(size_t)s2 * 32 + lane];
        float4 v3 = T4[(size_t)s3 * 32 + lane];
        acc.x += (v0.x + v1.x) + (v2.x + v3.x);
        acc.y += (v0.y + v1.y) + (v2.y + v3.y);
        acc.z += (v0.z + v1.z) + (v2.z + v3.z);
        acc.w += (v0.w + v1.w) + (v2.w + v3.w);
    }
    for (; p < pe; ++p) {
        float4 v = T4[(size_t)esrc[p] * 32 + lane];
        acc.x += v.x; acc.y += v.y; acc.z += v.z; acc.w += v.w;
    }
    const float4 b = ((const float4*)bias)[lane];
    float4 o;
    o.x = fmaxf(acc.x + b.x, 0.f);
    o.y = fmaxf(acc.y + b.y, 0.f);
    o.z = fmaxf(acc.z + b.z, 0.f);
    o.w = fmaxf(acc.w + b.w, 0.f);
    ((float4*)out)[(size_t)hw * 32 + lane] = o;
}

// F=32: one wave per node; 8 neighbor-groups x 8 lanes (each group gathers a
// different neighbor's 128B row); cross-group shfl_xor reduce. No divergence.
__global__ void agg_f32_fused_k(const float* __restrict__ T, const int* __restrict__ row_start,
                                const int* __restrict__ esrc, const float* __restrict__ bias,
                                float* __restrict__ out, int N) {
    const int wid = (blockIdx.x << 2) | (threadIdx.x >> 6);
    const int lane = threadIdx.x & 63;
    const int g = lane >> 3, l8 = lane & 7;
    if (wid >= N) return;
    const float4* T4 = (const float4*)T;
    float4 acc = make_float4(0.f, 0.f, 0.f, 0.f);
    const int p0 = row_start[wid];
    const int pe = row_start[wid + 1];
    for (int p = p0 + g; p < pe; p += 8) {
        int s = esrc[p];
        float4 v = T4[(size_t)s * 8 + l8];
        acc.x += v.x; acc.y += v.y; acc.z += v.z; acc.w += v.w;
    }
#pragma unroll
    for (int off = 8; off < 64; off <<= 1) {
        acc.x += __shfl_xor(acc.x, off);
        acc.y += __shfl_xor(acc.y, off);
        acc.z += __shfl_xor(acc.z, off);
        acc.w += __shfl_xor(acc.w, off);
    }
    if (g == 0) {
        float4 self = T4[(size_t)wid * 8 + l8];
        float4 b = ((const float4*)bias)[l8];
        float4 o;
        o.x = fmaxf(acc.x + self.x + b.x, 0.f);
        o.y = fmaxf(acc.y + self.y + b.y, 0.f);
        o.z = fmaxf(acc.z + self.z + b.z, 0.f);
        o.w = fmaxf(acc.w + self.w + b.w, 0.f);
        ((float4*)out)[(size_t)wid * 8 + l8] = o;
    }
}

// ---------------------------------------------------------------------------
// f32 vector-ALU GEMM: out[N,NC] = op(A[N,K] @ W[K,NC] [+ bias]), op = relu?
// bias may be nullptr (uniform branch).
// ---------------------------------------------------------------------------
template <int K, int NC, bool RELU>
__global__ __launch_bounds__(256) void gemm_k(const float* __restrict__ A,
                                              const float* __restrict__ W,
                                              const float* __restrict__ bias,
                                              float* __restrict__ out, int N) {
    constexpr int KB = 32;
    __shared__ float As[64][KB + 1];
    __shared__ float Bs[KB][NC];
    const int tid = threadIdx.x;
    const int row0 = blockIdx.x * 64;
    constexpr int CPT = NC / 16;
    const int tx = tid & 15, ty = tid >> 4;
    const int rbase = ty * 4, cbase = tx * CPT;

    float acc[4][CPT];
#pragma unroll
    for (int r = 0; r < 4; ++r)
#pragma unroll
        for (int c = 0; c < CPT; ++c) acc[r][c] = 0.f;

    for (int kc = 0; kc < K; kc += KB) {
#pragma unroll
        for (int i = 0; i < 2; ++i) {
            int idx = tid * 8 + i * 4;
            int r = idx >> 5, c = idx & 31;
            int gr = row0 + r;
            float4 v = make_float4(0.f, 0.f, 0.f, 0.f);
            if (gr < N) v = *(const float4*)&A[(size_t)gr * K + kc + c];
            As[r][c] = v.x; As[r][c + 1] = v.y; As[r][c + 2] = v.z; As[r][c + 3] = v.w;
        }
        constexpr int NF4 = (KB * NC) / (256 * 4);
#pragma unroll
        for (int i = 0; i < NF4; ++i) {
            int linear = (i * 256 + tid) * 4;
            int r = linear / NC, c = linear % NC;
            *(float4*)&Bs[r][c] = *(const float4*)&W[(size_t)(kc + r) * NC + c];
        }
        __syncthreads();
#pragma unroll
        for (int kk = 0; kk < KB; ++kk) {
            float a[4];
#pragma unroll
            for (int r = 0; r < 4; ++r) a[r] = As[rbase + r][kk];
            float b[CPT];
#pragma unroll
            for (int c = 0; c < CPT; ++c) b[c] = Bs[kk][cbase + c];
#pragma unroll
            for (int r = 0; r < 4; ++r)
#pragma unroll
                for (int c = 0; c < CPT; ++c) acc[r][c] += a[r] * b[c];
        }
        __syncthreads();
    }
#pragma unroll
    for (int r = 0; r < 4; ++r) {
        int gr = row0 + rbase + r;
        if (gr < N) {
#pragma unroll
            for (int c = 0; c < CPT; ++c) {
                float v = acc[r][c];
                if (bias) v += bias[cbase + c];
                if (RELU) v = fmaxf(v, 0.f);
                out[(size_t)gr * NC + cbase + c] = v;
            }
        }
    }
}

// ---------------------------------------------------------------------------
// BatchNorm: column sums/sumsq -> scale/shift -> fused apply + relu
// ---------------------------------------------------------------------------
template <int F>
__global__ void stats_k(const float* __restrict__ U, int N, float* __restrict__ sums) {
    constexpr int RPB = 256 / F;
    const int tid = threadIdx.x;
    const int col = tid % F;
    const int rsub = tid / F;
    float s = 0.f, q = 0.f;
    for (int r = blockIdx.x * RPB + rsub; r < N; r += gridDim.x * RPB) {
        float v = U[(size_t)r * F + col];
        s += v;
        q += v * v;
    }
    __shared__ float ls[256], lq[256];
    ls[tid] = s; lq[tid] = q;
    __syncthreads();
    if (tid < F) {
#pragma unroll
        for (int k = 1; k < RPB; ++k) { s += ls[tid + k * F]; q += lq[tid + k * F]; }
        atomicAdd(&sums[col], s);
        atomicAdd(&sums[F + col], q);
    }
}

template <int F>
__global__ void finalize_k(const float* __restrict__ sums, const float* __restrict__ g,
                           const float* __restrict__ be, int N,
                           float* __restrict__ scale, float* __restrict__ shift) {
    const int c = threadIdx.x;
    if (c < F) {
        float inv_n = 1.f / (float)N;
        float mean = sums[c] * inv_n;
        float var = sums[F + c] * inv_n - mean * mean;
        float sc = g[c] * rsqrtf(var + BN_EPS);
        scale[c] = sc;
        shift[c] = be[c] - mean * sc;
    }
}

template <int F>
__global__ void bnapply_k(const float* __restrict__ U, const float* __restrict__ scale,
                          const float* __restrict__ shift, float* __restrict__ out, int total4) {
    const float4* U4 = (const float4*)U;
    const float4* S4 = (const float4*)scale;
    const float4* H4 = (const float4*)shift;
    float4* O4 = (float4*)out;
    const int stride = gridDim.x * blockDim.x;
    for (int i = blockIdx.x * blockDim.x + threadIdx.x; i < total4; i += stride) {
        int c4 = i % (F / 4);
        float4 u = U4[i], sc = S4[c4], sh = H4[c4];
        float4 o;
        o.x = fmaxf(u.x * sc.x + sh.x, 0.f);
        o.y = fmaxf(u.y * sc.y + sh.y, 0.f);
        o.z = fmaxf(u.z * sc.z + sh.z, 0.f);
        o.w = fmaxf(u.w * sc.w + sh.w, 0.f);
        O4[i] = o;
    }
}

// ---------------------------------------------------------------------------
extern "C" void kernel_launch(void* const* d_in, const int* in_sizes, int n_in,
                              void* d_out, int out_size, void* d_ws, size_t ws_size,
                              hipStream_t stream) {
    const float* x   = (const float*)d_in[0];
    const int*   eb  = (const int*)d_in[1];
    const float* W1a = (const float*)d_in[2];
    const float* b1a = (const float*)d_in[3];
    const float* W1b = (const float*)d_in[4];
    const float* b1b = (const float*)d_in[5];
    const float* g1  = (const float*)d_in[6];
    const float* be1 = (const float*)d_in[7];
    const float* W2a = (const float*)d_in[8];
    const float* b2a = (const float*)d_in[9];
    const float* W2b = (const float*)d_in[10];
    const float* b2b = (const float*)d_in[11];
    const float* g2  = (const float*)d_in[12];
    const float* be2 = (const float*)d_in[13];
    float* out = (float*)d_out;

    const int N = in_sizes[0] / F_IN;  // 100000
    const int E = in_sizes[1] / 2;     // 3200000

    char* w = (char*)d_ws;
    size_t off = 0;
    auto alloc = [&](size_t bytes) -> void* {
        void* p = w + off;
        off = (off + bytes + 255) & ~(size_t)255;
        return p;
    };
    float* RA = (float*)alloc((size_t)N * H1 * 4);   // t1 / u1
    float* RB = (float*)alloc((size_t)N * H1 * 4);   // s1 / h1
    float* SA = (float*)alloc((size_t)N * H2 * 4);   // t2 / u2
    float* SB = (float*)alloc((size_t)N * H2 * 4);   // s2
    int* row_start = (int*)alloc((size_t)(N + 1) * 4);
    int* cnt    = (int*)alloc((size_t)N * 4);
    int* cursor = (int*)alloc((size_t)N * 4);
    int* incl   = (int*)alloc((size_t)N * 4);
    int* esrc   = (int*)alloc((size_t)E * 4);
    int* bsum   = (int*)alloc(4096);
    int* flag   = (int*)alloc(256);
    float* sums1 = (float*)alloc(2 * H1 * 4);
    float* sc1   = (float*)alloc(H1 * 4);
    float* sh1   = (float*)alloc(H1 * 4);
    float* sums2 = (float*)alloc(2 * H2 * 4);
    float* sc2   = (float*)alloc(H2 * 4);
    float* sh2   = (float*)alloc(H2 * 4);

    hipMemsetAsync(cnt, 0, (size_t)N * 4, stream);
    hipMemsetAsync(cursor, 0, (size_t)N * 4, stream);
    hipMemsetAsync(sums1, 0, 2 * H1 * 4, stream);
    hipMemsetAsync(sums2, 0, 2 * H2 * 4, stream);

    // --- CSR build (by dst) ---
    detect_k<<<1, 128, 0, stream>>>(eb, flag);
    hist_k<<<2048, 256, 0, stream>>>(eb, flag, E, N, cnt);
    const int nb = (N + 1023) / 1024;
    scan1_k<<<nb, 1024, 0, stream>>>(cnt, N, incl, bsum);
    scan2_k<<<1, 64, 0, stream>>>(bsum, nb);
    scan3_k<<<nb, 1024, 0, stream>>>(incl, bsum, N, row_start);
    scatter_k<<<2048, 256, 0, stream>>>(eb, flag, E, N, row_start, cursor, esrc);

    // --- layer 1:  t1 = x@W1a;  s1 = relu(t1 + agg(t1) + b1a);
    //               u1 = s1@W1b + b1b;  h1 = relu(BN(u1))
    gemm_k<256, 128, false><<<(N + 63) / 64, 256, 0, stream>>>(x, W1a, nullptr, RA, N);
    agg_f128_fused_k<<<(N + 7) / 8, 256, 0, stream>>>(RA, row_start, esrc, b1a, RB, N);
    gemm_k<128, 128, false><<<(N + 63) / 64, 256, 0, stream>>>(RB, W1b, b1b, RA, N);
    stats_k<128><<<512, 256, 0, stream>>>(RA, N, sums1);
    finalize_k<128><<<1, 128, 0, stream>>>(sums1, g1, be1, N, sc1, sh1);
    bnapply_k<128><<<12500, 256, 0, stream>>>(RA, sc1, sh1, RB, N * H1 / 4);

    // --- layer 2:  t2 = h1@W2a;  s2 = relu(t2 + agg(t2) + b2a);
    //               u2 = s2@W2b + b2b;  out = relu(BN(u2))
    gemm_k<128, 32, false><<<(N + 63) / 64, 256, 0, stream>>>(RB, W2a, nullptr, SA, N);
    agg_f32_fused_k<<<(N + 3) / 4, 256, 0, stream>>>(SA, row_start, esrc, b2a, SB, N);
    gemm_k<32, 32, false><<<(N + 63) / 64, 256, 0, stream>>>(SB, W2b, b2b, SA, N);
    stats_k<32><<<512, 256, 0, stream>>>(SA, N, sums2);
    finalize_k<32><<<1, 32, 0, stream>>>(sums2, g2, be2, N, sc2, sh2);
    bnapply_k<32><<<3125, 256, 0, stream>>>(SA, sc2, sh2, out, N * H2 / 4);
}

// Round 3
// 713.502 us; speedup vs baseline: 1.7893x; 1.2745x over previous
//
#include <hip/hip_runtime.h>

#define F_IN 256
#define H1 128
#define H2 32
#define BN_EPS 1e-5f

typedef short bf16x8 __attribute__((ext_vector_type(8)));
typedef float f32x4 __attribute__((ext_vector_type(4)));

// f32 -> bf16 round-to-nearest-even (data has no NaN)
__device__ __forceinline__ ushort f2bf(float f) {
    uint u = __float_as_uint(f);
    return (ushort)((u + 0x7FFFu + ((u >> 16) & 1u)) >> 16);
}
__device__ __forceinline__ uint pack2(float a, float b) {
    return (uint)f2bf(a) | ((uint)f2bf(b) << 16);
}
// unpack u32 = 2 bf16 -> 2 f32
__device__ __forceinline__ void unpack2(uint u, float& a, float& b) {
    a = __uint_as_float(u << 16);
    b = __uint_as_float(u & 0xFFFF0000u);
}

// ---------------------------------------------------------------------------
// edge_index dtype detection (int64 little-endian -> odd words all zero)
// ---------------------------------------------------------------------------
__global__ void detect_k(const int* __restrict__ eb, int* __restrict__ flag) {
    __shared__ int nz;
    if (threadIdx.x == 0) nz = 0;
    __syncthreads();
    if (eb[2 * threadIdx.x + 1] != 0) atomicAdd(&nz, 1);
    __syncthreads();
    if (threadIdx.x == 0) flag[0] = (nz == 0) ? 1 : 0;
}

__device__ __forceinline__ int clampN(int v, int N) {
    return v < 0 ? 0 : (v >= N ? N - 1 : v);
}

__global__ void hist_k(const int* __restrict__ eb, const int* __restrict__ flag,
                       int E, int N, int* __restrict__ cnt) {
    const int is64 = flag[0];
    const int stride = gridDim.x * blockDim.x;
    for (int e = blockIdx.x * blockDim.x + threadIdx.x; e < E; e += stride) {
        int d = is64 ? eb[2 * (E + e)] : eb[E + e];
        d = clampN(d, N);
        atomicAdd(&cnt[d], 1);
    }
}

__global__ void scan1_k(const int* __restrict__ cnt, int N,
                        int* __restrict__ incl, int* __restrict__ bsum) {
    __shared__ int sm[1024];
    const int tid = threadIdx.x;
    const int i = blockIdx.x * 1024 + tid;
    sm[tid] = (i < N) ? cnt[i] : 0;
    __syncthreads();
    for (int off = 1; off < 1024; off <<= 1) {
        int t = (tid >= off) ? sm[tid - off] : 0;
        __syncthreads();
        sm[tid] += t;
        __syncthreads();
    }
    if (i < N) incl[i] = sm[tid];
    if (tid == 1023) bsum[blockIdx.x] = sm[1023];
}

__global__ void scan2_k(int* __restrict__ bsum, int nb) {
    if (blockIdx.x == 0 && threadIdx.x == 0) {
        int acc = 0;
        for (int i = 0; i < nb; ++i) { int v = bsum[i]; bsum[i] = acc; acc += v; }
    }
}

__global__ void scan3_k(const int* __restrict__ incl, const int* __restrict__ bsum,
                        int N, int* __restrict__ row_start) {
    const int i = blockIdx.x * 1024 + threadIdx.x;
    if (i < N) row_start[i + 1] = incl[i] + bsum[blockIdx.x];
    if (i == 0) row_start[0] = 0;
}

__global__ void scatter_k(const int* __restrict__ eb, const int* __restrict__ flag,
                          int E, int N, const int* __restrict__ row_start,
                          int* __restrict__ cursor, int* __restrict__ esrc) {
    const int is64 = flag[0];
    const int stride = gridDim.x * blockDim.x;
    for (int e = blockIdx.x * blockDim.x + threadIdx.x; e < E; e += stride) {
        int s = is64 ? eb[2 * e] : eb[e];
        int d = is64 ? eb[2 * (E + e)] : eb[E + e];
        s = clampN(s, N);
        d = clampN(d, N);
        int pos = row_start[d] + atomicAdd(&cursor[d], 1);
        esrc[pos] = s;
    }
}

// ---------------------------------------------------------------------------
// casts
// ---------------------------------------------------------------------------
// f32 -> bf16, 4 elems/thread (float4 -> uint2)
__global__ void cast_x_k(const float* __restrict__ src, ushort* __restrict__ dst, int total4) {
    const int stride = gridDim.x * blockDim.x;
    const float4* S4 = (const float4*)src;
    uint2* D2 = (uint2*)dst;
    for (int i = blockIdx.x * blockDim.x + threadIdx.x; i < total4; i += stride) {
        float4 v = S4[i];
        D2[i] = make_uint2(pack2(v.x, v.y), pack2(v.z, v.w));
    }
}

// W[K][NC] f32 -> WT[NC][K] bf16 (tiny)
__global__ void transpose_cast_k(const float* __restrict__ src, int K, int NC,
                                 ushort* __restrict__ dst) {
    const int idx = blockIdx.x * blockDim.x + threadIdx.x;
    if (idx < K * NC) {
        int k = idx / NC, c = idx % NC;
        dst[c * K + k] = f2bf(src[idx]);
    }
}

// ---------------------------------------------------------------------------
// MFMA GEMM: out[N,NC] = A[N,K] @ WT[NC,K]^T (+ bias). A,WT bf16; acc f32.
// No LDS: A frag = contiguous 16B lane load from node-major A;
//         B frag = contiguous 16B lane load from col-major WT (L1/L2-resident).
// Fragment maps (guide-verified): A: row=lane&15, k=8*(lane>>4)+i;
//                                 C/D: col=lane&15, row=(lane>>4)*4+j.
// ---------------------------------------------------------------------------
template <int K, int NC, bool BIAS, bool OUT_BF16>
__global__ __launch_bounds__(256) void gemm_mfma_k(const ushort* __restrict__ A,
                                                   const ushort* __restrict__ WT,
                                                   const float* __restrict__ bias,
                                                   void* __restrict__ outv, int N) {
    constexpr int NF = NC / 16;
    const int lane = threadIdx.x & 63;
    const int wave = threadIdx.x >> 6;
    const int row0 = blockIdx.x * 64 + wave * 16;   // this wave's 16-row strip
    const int col = lane & 15;
    const int k0 = (lane >> 4) * 8;

    int arow = row0 + col;                           // A-frag row for this lane
    if (arow >= N) arow = N - 1;

    f32x4 acc[NF];
#pragma unroll
    for (int f = 0; f < NF; ++f) acc[f] = (f32x4){0.f, 0.f, 0.f, 0.f};

#pragma unroll
    for (int kc = 0; kc < K; kc += 32) {
        bf16x8 af = *(const bf16x8*)&A[(size_t)arow * K + kc + k0];
#pragma unroll
        for (int f = 0; f < NF; ++f) {
            bf16x8 bf = *(const bf16x8*)&WT[(size_t)(f * 16 + col) * K + kc + k0];
            acc[f] = __builtin_amdgcn_mfma_f32_16x16x32_bf16(af, bf, acc[f], 0, 0, 0);
        }
    }

    const int crow = row0 + (lane >> 4) * 4;
#pragma unroll
    for (int f = 0; f < NF; ++f) {
        const int c = f * 16 + col;
        float bv = BIAS ? bias[c] : 0.f;
#pragma unroll
        for (int j = 0; j < 4; ++j) {
            int r = crow + j;
            if (r < N) {
                float v = acc[f][j] + bv;
                if (OUT_BF16) ((ushort*)outv)[(size_t)r * NC + c] = f2bf(v);
                else          ((float*)outv)[(size_t)r * NC + c] = v;
            }
        }
    }
}

// ---------------------------------------------------------------------------
// fused aggregation on bf16 rows: out = relu(T[i] + sum_j T[j] + bias), bf16 out
// F=128: half-wave (32 lanes x 8B uint2 = 256B row) per node.
// ---------------------------------------------------------------------------
__global__ void agg_f128b_k(const ushort* __restrict__ T, const int* __restrict__ row_start,
                            const int* __restrict__ esrc, const float* __restrict__ bias,
                            ushort* __restrict__ out, int N) {
    const int hw = (blockIdx.x << 3) | (threadIdx.x >> 5);
    const int lane = threadIdx.x & 31;
    if (hw >= N) return;
    const uint2* T2 = (const uint2*)T;
    uint2 sv = T2[(size_t)hw * 32 + lane];
    float a0, a1, a2, a3;
    unpack2(sv.x, a0, a1);
    unpack2(sv.y, a2, a3);
    int p = row_start[hw];
    const int pe = row_start[hw + 1];
    for (; p + 3 < pe; p += 4) {
        int s0 = esrc[p], s1 = esrc[p + 1], s2 = esrc[p + 2], s3 = esrc[p + 3];
        uint2 v0 = T2[(size_t)s0 * 32 + lane];
        uint2 v1 = T2[(size_t)s1 * 32 + lane];
        uint2 v2 = T2[(size_t)s2 * 32 + lane];
        uint2 v3 = T2[(size_t)s3 * 32 + lane];
        float x0, x1, x2, x3;
        unpack2(v0.x, x0, x1); unpack2(v0.y, x2, x3);
        a0 += x0; a1 += x1; a2 += x2; a3 += x3;
        unpack2(v1.x, x0, x1); unpack2(v1.y, x2, x3);
        a0 += x0; a1 += x1; a2 += x2; a3 += x3;
        unpack2(v2.x, x0, x1); unpack2(v2.y, x2, x3);
        a0 += x0; a1 += x1; a2 += x2; a3 += x3;
        unpack2(v3.x, x0, x1); unpack2(v3.y, x2, x3);
        a0 += x0; a1 += x1; a2 += x2; a3 += x3;
    }
    for (; p < pe; ++p) {
        uint2 v = T2[(size_t)esrc[p] * 32 + lane];
        float x0, x1, x2, x3;
        unpack2(v.x, x0, x1); unpack2(v.y, x2, x3);
        a0 += x0; a1 += x1; a2 += x2; a3 += x3;
    }
    const float4 b = ((const float4*)bias)[lane];
    a0 = fmaxf(a0 + b.x, 0.f);
    a1 = fmaxf(a1 + b.y, 0.f);
    a2 = fmaxf(a2 + b.z, 0.f);
    a3 = fmaxf(a3 + b.w, 0.f);
    ((uint2*)out)[(size_t)hw * 32 + lane] = make_uint2(pack2(a0, a1), pack2(a2, a3));
}

// F=32: wave per node; 8 neighbor-groups x 8 lanes (8B uint2 each = 64B row);
// cross-group shfl_xor reduce.
__global__ void agg_f32b_k(const ushort* __restrict__ T, const int* __restrict__ row_start,
                           const int* __restrict__ esrc, const float* __restrict__ bias,
                           ushort* __restrict__ out, int N) {
    const int wid = (blockIdx.x << 2) | (threadIdx.x >> 6);
    const int lane = threadIdx.x & 63;
    const int g = lane >> 3, l8 = lane & 7;
    if (wid >= N) return;
    const uint2* T2 = (const uint2*)T;
    float a0 = 0.f, a1 = 0.f, a2 = 0.f, a3 = 0.f;
    const int p0 = row_start[wid];
    const int pe = row_start[wid + 1];
    for (int p = p0 + g; p < pe; p += 8) {
        uint2 v = T2[(size_t)esrc[p] * 8 + l8];
        float x0, x1, x2, x3;
        unpack2(v.x, x0, x1); unpack2(v.y, x2, x3);
        a0 += x0; a1 += x1; a2 += x2; a3 += x3;
    }
#pragma unroll
    for (int off = 8; off < 64; off <<= 1) {
        a0 += __shfl_xor(a0, off);
        a1 += __shfl_xor(a1, off);
        a2 += __shfl_xor(a2, off);
        a3 += __shfl_xor(a3, off);
    }
    if (g == 0) {
        uint2 sv = T2[(size_t)wid * 8 + l8];
        float s0, s1, s2, s3;
        unpack2(sv.x, s0, s1); unpack2(sv.y, s2, s3);
        const float4 b = ((const float4*)bias)[l8];
        a0 = fmaxf(a0 + s0 + b.x, 0.f);
        a1 = fmaxf(a1 + s1 + b.y, 0.f);
        a2 = fmaxf(a2 + s2 + b.z, 0.f);
        a3 = fmaxf(a3 + s3 + b.w, 0.f);
        ((uint2*)out)[(size_t)wid * 8 + l8] = make_uint2(pack2(a0, a1), pack2(a2, a3));
    }
}

// ---------------------------------------------------------------------------
// BatchNorm: column sums/sumsq (f32 input) -> scale/shift -> apply+relu
// ---------------------------------------------------------------------------
template <int F>
__global__ void stats_k(const float* __restrict__ U, int N, float* __restrict__ sums) {
    constexpr int RPB = 256 / F;
    const int tid = threadIdx.x;
    const int col = tid % F;
    const int rsub = tid / F;
    float s = 0.f, q = 0.f;
    for (int r = blockIdx.x * RPB + rsub; r < N; r += gridDim.x * RPB) {
        float v = U[(size_t)r * F + col];
        s += v;
        q += v * v;
    }
    __shared__ float ls[256], lq[256];
    ls[tid] = s; lq[tid] = q;
    __syncthreads();
    if (tid < F) {
#pragma unroll
        for (int k = 1; k < RPB; ++k) { s += ls[tid + k * F]; q += lq[tid + k * F]; }
        atomicAdd(&sums[col], s);
        atomicAdd(&sums[F + col], q);
    }
}

template <int F>
__global__ void finalize_k(const float* __restrict__ sums, const float* __restrict__ g,
                           const float* __restrict__ be, int N,
                           float* __restrict__ scale, float* __restrict__ shift) {
    const int c = threadIdx.x;
    if (c < F) {
        float inv_n = 1.f / (float)N;
        float mean = sums[c] * inv_n;
        float var = sums[F + c] * inv_n - mean * mean;
        float sc = g[c] * rsqrtf(var + BN_EPS);
        scale[c] = sc;
        shift[c] = be[c] - mean * sc;
    }
}

// apply + relu, f32 in -> f32 out
template <int F>
__global__ void bnapply_k(const float* __restrict__ U, const float* __restrict__ scale,
                          const float* __restrict__ shift, float* __restrict__ out, int total4) {
    const float4* U4 = (const float4*)U;
    const float4* S4 = (const float4*)scale;
    const float4* H4 = (const float4*)shift;
    float4* O4 = (float4*)out;
    const int stride = gridDim.x * blockDim.x;
    for (int i = blockIdx.x * blockDim.x + threadIdx.x; i < total4; i += stride) {
        int c4 = i % (F / 4);
        float4 u = U4[i], sc = S4[c4], sh = H4[c4];
        float4 o;
        o.x = fmaxf(u.x * sc.x + sh.x, 0.f);
        o.y = fmaxf(u.y * sc.y + sh.y, 0.f);
        o.z = fmaxf(u.z * sc.z + sh.z, 0.f);
        o.w = fmaxf(u.w * sc.w + sh.w, 0.f);
        O4[i] = o;
    }
}

// apply + relu, f32 in -> bf16 out
template <int F>
__global__ void bnapply_bf_k(const float* __restrict__ U, const float* __restrict__ scale,
                             const float* __restrict__ shift, ushort* __restrict__ out,
                             int total4) {
    const float4* U4 = (const float4*)U;
    const float4* S4 = (const float4*)scale;
    const float4* H4 = (const float4*)shift;
    uint2* O2 = (uint2*)out;
    const int stride = gridDim.x * blockDim.x;
    for (int i = blockIdx.x * blockDim.x + threadIdx.x; i < total4; i += stride) {
        int c4 = i % (F / 4);
        float4 u = U4[i], sc = S4[c4], sh = H4[c4];
        float o0 = fmaxf(u.x * sc.x + sh.x, 0.f);
        float o1 = fmaxf(u.y * sc.y + sh.y, 0.f);
        float o2 = fmaxf(u.z * sc.z + sh.z, 0.f);
        float o3 = fmaxf(u.w * sc.w + sh.w, 0.f);
        O2[i] = make_uint2(pack2(o0, o1), pack2(o2, o3));
    }
}

// ---------------------------------------------------------------------------
extern "C" void kernel_launch(void* const* d_in, const int* in_sizes, int n_in,
                              void* d_out, int out_size, void* d_ws, size_t ws_size,
                              hipStream_t stream) {
    const float* x   = (const float*)d_in[0];
    const int*   eb  = (const int*)d_in[1];
    const float* W1a = (const float*)d_in[2];
    const float* b1a = (const float*)d_in[3];
    const float* W1b = (const float*)d_in[4];
    const float* b1b = (const float*)d_in[5];
    const float* g1  = (const float*)d_in[6];
    const float* be1 = (const float*)d_in[7];
    const float* W2a = (const float*)d_in[8];
    const float* b2a = (const float*)d_in[9];
    const float* W2b = (const float*)d_in[10];
    const float* b2b = (const float*)d_in[11];
    const float* g2  = (const float*)d_in[12];
    const float* be2 = (const float*)d_in[13];
    float* out = (float*)d_out;

    const int N = in_sizes[0] / F_IN;  // 100000
    const int E = in_sizes[1] / 2;     // 3200000

    char* w = (char*)d_ws;
    size_t off = 0;
    auto alloc = [&](size_t bytes) -> void* {
        void* p = w + off;
        off = (off + bytes + 255) & ~(size_t)255;
        return p;
    };
    // big buffers with lifetime reuse:
    ushort* B0 = (ushort*)alloc((size_t)N * F_IN * 2);  // xb -> s1b -> t2b
    ushort* B1 = (ushort*)alloc((size_t)N * H1 * 2);    // t1b -> h1b
    float*  B2 = (float*)alloc((size_t)N * H1 * 4);     // u1 -> {s2b, u2}
    ushort* s2b = (ushort*)B2;                          // N*H2 bf16 (6.4 MB)
    float*  u2  = (float*)((char*)B2 + (size_t)N * H2 * 2);  // N*H2 f32, disjoint

    int* row_start = (int*)alloc((size_t)(N + 1) * 4);
    int* cnt    = (int*)alloc((size_t)N * 4);
    int* cursor = (int*)alloc((size_t)N * 4);
    int* incl   = (int*)alloc((size_t)N * 4);
    int* esrc   = (int*)alloc((size_t)E * 4);
    int* bsum   = (int*)alloc(4096);
    int* flag   = (int*)alloc(256);
    ushort* w1aT = (ushort*)alloc(F_IN * H1 * 2);
    ushort* w1bT = (ushort*)alloc(H1 * H1 * 2);
    ushort* w2aT = (ushort*)alloc(H1 * H2 * 2);
    ushort* w2bT = (ushort*)alloc(H2 * H2 * 2);
    float* sums1 = (float*)alloc(2 * H1 * 4);
    float* sc1   = (float*)alloc(H1 * 4);
    float* sh1   = (float*)alloc(H1 * 4);
    float* sums2 = (float*)alloc(2 * H2 * 4);
    float* sc2   = (float*)alloc(H2 * 4);
    float* sh2   = (float*)alloc(H2 * 4);

    hipMemsetAsync(cnt, 0, (size_t)N * 4, stream);
    hipMemsetAsync(cursor, 0, (size_t)N * 4, stream);
    hipMemsetAsync(sums1, 0, 2 * H1 * 4, stream);
    hipMemsetAsync(sums2, 0, 2 * H2 * 4, stream);

    // --- casts ---
    cast_x_k<<<4096, 256, 0, stream>>>(x, B0, N * F_IN / 4);
    transpose_cast_k<<<(F_IN * H1 + 255) / 256, 256, 0, stream>>>(W1a, F_IN, H1, w1aT);
    transpose_cast_k<<<(H1 * H1 + 255) / 256, 256, 0, stream>>>(W1b, H1, H1, w1bT);
    transpose_cast_k<<<(H1 * H2 + 255) / 256, 256, 0, stream>>>(W2a, H1, H2, w2aT);
    transpose_cast_k<<<(H2 * H2 + 255) / 256, 256, 0, stream>>>(W2b, H2, H2, w2bT);

    // --- CSR build (by dst) ---
    detect_k<<<1, 128, 0, stream>>>(eb, flag);
    hist_k<<<2048, 256, 0, stream>>>(eb, flag, E, N, cnt);
    const int nb = (N + 1023) / 1024;
    scan1_k<<<nb, 1024, 0, stream>>>(cnt, N, incl, bsum);
    scan2_k<<<1, 64, 0, stream>>>(bsum, nb);
    scan3_k<<<nb, 1024, 0, stream>>>(incl, bsum, N, row_start);
    scatter_k<<<2048, 256, 0, stream>>>(eb, flag, E, N, row_start, cursor, esrc);

    const int gemm_grid = (N + 63) / 64;

    // --- layer 1 ---
    // t1 = xb @ W1a  (bf16 out, in B1)
    gemm_mfma_k<F_IN, H1, false, true><<<gemm_grid, 256, 0, stream>>>(B0, w1aT, nullptr, B1, N);
    // s1 = relu(t1 + agg(t1) + b1a)  (bf16 out, in B0; xb dead)
    agg_f128b_k<<<(N + 7) / 8, 256, 0, stream>>>(B1, row_start, esrc, b1a, B0, N);
    // u1 = s1 @ W1b + b1b  (f32 out, in B2)
    gemm_mfma_k<H1, H1, true, false><<<gemm_grid, 256, 0, stream>>>(B0, w1bT, b1b, B2, N);
    stats_k<H1><<<512, 256, 0, stream>>>(B2, N, sums1);
    finalize_k<H1><<<1, 128, 0, stream>>>(sums1, g1, be1, N, sc1, sh1);
    // h1 = relu(BN(u1))  (bf16 out, in B1; t1 dead)
    bnapply_bf_k<H1><<<12500, 256, 0, stream>>>(B2, sc1, sh1, B1, N * H1 / 4);

    // --- layer 2 ---
    // t2 = h1 @ W2a  (bf16 out, in B0; s1 dead)
    gemm_mfma_k<H1, H2, false, true><<<gemm_grid, 256, 0, stream>>>(B1, w2aT, nullptr, B0, N);
    // s2 = relu(t2 + agg(t2) + b2a)  (bf16 out, s2b in B2; u1 dead)
    agg_f32b_k<<<(N + 3) / 4, 256, 0, stream>>>(B0, row_start, esrc, b2a, s2b, N);
    // u2 = s2 @ W2b + b2b  (f32 out, u2 in B2 disjoint region)
    gemm_mfma_k<H2, H2, true, false><<<gemm_grid, 256, 0, stream>>>(s2b, w2bT, b2b, u2, N);
    stats_k<H2><<<512, 256, 0, stream>>>(u2, N, sums2);
    finalize_k<H2><<<1, 32, 0, stream>>>(sums2, g2, be2, N, sc2, sh2);
    bnapply_k<H2><<<3125, 256, 0, stream>>>(u2, sc2, sh2, out, N * H2 / 4);
}

// Round 4
// 507.788 us; speedup vs baseline: 2.5141x; 1.4051x over previous
//
#include <hip/hip_runtime.h>

#define F_IN 256
#define H1 128
#define H2 32
#define BN_EPS 1e-5f
#define BSHIFT 9
#define BCAP 32768

typedef short bf16x8 __attribute__((ext_vector_type(8)));
typedef float f32x4 __attribute__((ext_vector_type(4)));

// f32 -> bf16 round-to-nearest-even (data has no NaN)
__device__ __forceinline__ ushort f2bf(float f) {
    uint u = __float_as_uint(f);
    return (ushort)((u + 0x7FFFu + ((u >> 16) & 1u)) >> 16);
}
__device__ __forceinline__ uint pack2(float a, float b) {
    return (uint)f2bf(a) | ((uint)f2bf(b) << 16);
}
__device__ __forceinline__ void unpack2(uint u, float& a, float& b) {
    a = __uint_as_float(u << 16);
    b = __uint_as_float(u & 0xFFFF0000u);
}

// ---------------------------------------------------------------------------
// edge_index dtype detection (int64 little-endian -> odd words all zero)
// ---------------------------------------------------------------------------
__global__ void detect_k(const int* __restrict__ eb, int* __restrict__ flag) {
    __shared__ int nz;
    if (threadIdx.x == 0) nz = 0;
    __syncthreads();
    if (eb[2 * threadIdx.x + 1] != 0) atomicAdd(&nz, 1);
    __syncthreads();
    if (threadIdx.x == 0) flag[0] = (nz == 0) ? 1 : 0;
}

__device__ __forceinline__ int clampN(int v, int N) {
    return v < 0 ? 0 : (v >= N ? N - 1 : v);
}

// ---------------------------------------------------------------------------
// CSR build, two-level binning.
// Phase A: bin edges by dst>>9 into fixed-cap bucket regions; 4B records
// src|(dstlow<<17). Per-block LDS histogram -> ONE global atomic per
// (block,bucket); block's writes per bucket are contiguous sub-ranges.
// ---------------------------------------------------------------------------
__global__ __launch_bounds__(256) void binA_k(const int* __restrict__ eb,
                                              const int* __restrict__ flag,
                                              int E, int N, int NBUCK,
                                              int* __restrict__ bucket_cursor,
                                              uint* __restrict__ rec) {
    __shared__ int lcnt[512];
    __shared__ int lbase[512];
    const int tid = threadIdx.x;
    const int is64 = flag[0];
    const int stride = gridDim.x * blockDim.x;
    const int start = blockIdx.x * blockDim.x + tid;
    for (int i = tid; i < NBUCK; i += 256) lcnt[i] = 0;
    __syncthreads();
    for (int e = start; e < E; e += stride) {
        int d = is64 ? eb[2 * (E + e)] : eb[E + e];
        d = clampN(d, N);
        atomicAdd(&lcnt[d >> BSHIFT], 1);
    }
    __syncthreads();
    for (int i = tid; i < NBUCK; i += 256) {
        lbase[i] = atomicAdd(&bucket_cursor[i], lcnt[i]);
        lcnt[i] = 0;
    }
    __syncthreads();
    for (int e = start; e < E; e += stride) {
        int s = is64 ? eb[2 * e] : eb[e];
        int d = is64 ? eb[2 * (E + e)] : eb[E + e];
        s = clampN(s, N);
        d = clampN(d, N);
        int bk = d >> BSHIFT;
        int rank = atomicAdd(&lcnt[bk], 1) + lbase[bk];
        if (rank < BCAP)
            rec[(size_t)bk * BCAP + rank] = (uint)s | ((uint)(d & 511) << 17);
    }
}

// exclusive scan over bucket counts (<=512, single thread is fine)
__global__ void bscan_k(const int* __restrict__ bucket_cursor, int NBUCK, int N,
                        int* __restrict__ ebase, int* __restrict__ row_start) {
    if (threadIdx.x == 0 && blockIdx.x == 0) {
        int acc = 0;
        for (int i = 0; i < NBUCK; ++i) {
            ebase[i] = acc;
            int c = bucket_cursor[i];
            acc += (c < BCAP) ? c : BCAP;
        }
        ebase[NBUCK] = acc;
        row_start[N] = acc;
    }
}

// Phase B: one block per bucket. LDS histogram of 512 nodes -> LDS scan ->
// writes row_start for its node range and scatters src into a ~64KB
// single-block esrc slice (L2-combined, no cross-XCD sharing).
__global__ __launch_bounds__(256) void binB_k(const uint* __restrict__ rec,
                                              const int* __restrict__ bucket_cursor,
                                              const int* __restrict__ ebase,
                                              int N, int* __restrict__ row_start,
                                              int* __restrict__ esrc) {
    __shared__ int cntA[512];
    __shared__ int cntB[512];
    const int bk = blockIdx.x;
    const int tid = threadIdx.x;
    int cnt = bucket_cursor[bk];
    if (cnt > BCAP) cnt = BCAP;
    const uint* r = rec + (size_t)bk * BCAP;
    const int base = ebase[bk];
    for (int i = tid; i < 512; i += 256) cntA[i] = 0;
    __syncthreads();
    for (int i = tid; i < cnt; i += 256) atomicAdd(&cntA[r[i] >> 17], 1);
    __syncthreads();
    // inclusive scan over 512 entries, ping-pong
    int* src = cntA;
    int* dst = cntB;
    for (int off = 1; off < 512; off <<= 1) {
        for (int i = tid; i < 512; i += 256)
            dst[i] = src[i] + (i >= off ? src[i - off] : 0);
        __syncthreads();
        int* t = src; src = dst; dst = t;
    }
    // src = inclusive scan; exclusive[i] = i ? src[i-1] : 0
    const int n0 = bk << BSHIFT;
    for (int i = tid; i < 512; i += 256) {
        int node = n0 + i;
        if (node < N) row_start[node] = base + (i ? src[i - 1] : 0);
    }
    for (int i = tid; i < 512; i += 256) dst[i] = 0;  // reuse as cursors
    __syncthreads();
    for (int i = tid; i < cnt; i += 256) {
        uint rv = r[i];
        int dl = rv >> 17;
        int rank = atomicAdd(&dst[dl], 1);
        esrc[base + (dl ? src[dl - 1] : 0) + rank] = (int)(rv & 0x1FFFFu);
    }
}

// ---------------------------------------------------------------------------
// W[K][NC] f32 -> WT[NC][K] bf16 (tiny)
// ---------------------------------------------------------------------------
__global__ void transpose_cast_k(const float* __restrict__ src, int K, int NC,
                                 ushort* __restrict__ dst) {
    const int idx = blockIdx.x * blockDim.x + threadIdx.x;
    if (idx < K * NC) {
        int k = idx / NC, c = idx % NC;
        dst[c * K + k] = f2bf(src[idx]);
    }
}

// ---------------------------------------------------------------------------
// MFMA GEMM (bf16 A): out[N,NC] = A[N,K] @ WT[NC,K]^T (+bias). acc f32.
// ---------------------------------------------------------------------------
template <int K, int NC, bool BIAS, bool OUT_BF16>
__global__ __launch_bounds__(256) void gemm_mfma_k(const ushort* __restrict__ A,
                                                   const ushort* __restrict__ WT,
                                                   const float* __restrict__ bias,
                                                   void* __restrict__ outv, int N) {
    constexpr int NF = NC / 16;
    const int lane = threadIdx.x & 63;
    const int wave = threadIdx.x >> 6;
    const int row0 = blockIdx.x * 64 + wave * 16;
    const int col = lane & 15;
    const int k0 = (lane >> 4) * 8;

    int arow = row0 + col;
    if (arow >= N) arow = N - 1;

    f32x4 acc[NF];
#pragma unroll
    for (int f = 0; f < NF; ++f) acc[f] = (f32x4){0.f, 0.f, 0.f, 0.f};

#pragma unroll
    for (int kc = 0; kc < K; kc += 32) {
        bf16x8 af = *(const bf16x8*)&A[(size_t)arow * K + kc + k0];
#pragma unroll
        for (int f = 0; f < NF; ++f) {
            bf16x8 bf = *(const bf16x8*)&WT[(size_t)(f * 16 + col) * K + kc + k0];
            acc[f] = __builtin_amdgcn_mfma_f32_16x16x32_bf16(af, bf, acc[f], 0, 0, 0);
        }
    }

    const int crow = row0 + (lane >> 4) * 4;
#pragma unroll
    for (int f = 0; f < NF; ++f) {
        const int c = f * 16 + col;
        float bv = BIAS ? bias[c] : 0.f;
#pragma unroll
        for (int j = 0; j < 4; ++j) {
            int rr = crow + j;
            if (rr < N) {
                float v = acc[f][j] + bv;
                if (OUT_BF16) ((ushort*)outv)[(size_t)rr * NC + c] = f2bf(v);
                else          ((float*)outv)[(size_t)rr * NC + c] = v;
            }
        }
    }
}

// MFMA GEMM with f32 A (packs to bf16 in-register; saves the cast pass)
template <int K, int NC, bool BIAS, bool OUT_BF16>
__global__ __launch_bounds__(256) void gemm_mfma_f32a_k(const float* __restrict__ Af,
                                                        const ushort* __restrict__ WT,
                                                        const float* __restrict__ bias,
                                                        void* __restrict__ outv, int N) {
    constexpr int NF = NC / 16;
    const int lane = threadIdx.x & 63;
    const int wave = threadIdx.x >> 6;
    const int row0 = blockIdx.x * 64 + wave * 16;
    const int col = lane & 15;
    const int k0 = (lane >> 4) * 8;

    int arow = row0 + col;
    if (arow >= N) arow = N - 1;

    f32x4 acc[NF];
#pragma unroll
    for (int f = 0; f < NF; ++f) acc[f] = (f32x4){0.f, 0.f, 0.f, 0.f};

#pragma unroll
    for (int kc = 0; kc < K; kc += 32) {
        const float* ap = &Af[(size_t)arow * K + kc + k0];
        float4 p = *(const float4*)ap;
        float4 q = *(const float4*)(ap + 4);
        bf16x8 af;
        af[0] = (short)f2bf(p.x); af[1] = (short)f2bf(p.y);
        af[2] = (short)f2bf(p.z); af[3] = (short)f2bf(p.w);
        af[4] = (short)f2bf(q.x); af[5] = (short)f2bf(q.y);
        af[6] = (short)f2bf(q.z); af[7] = (short)f2bf(q.w);
#pragma unroll
        for (int f = 0; f < NF; ++f) {
            bf16x8 bf = *(const bf16x8*)&WT[(size_t)(f * 16 + col) * K + kc + k0];
            acc[f] = __builtin_amdgcn_mfma_f32_16x16x32_bf16(af, bf, acc[f], 0, 0, 0);
        }
    }

    const int crow = row0 + (lane >> 4) * 4;
#pragma unroll
    for (int f = 0; f < NF; ++f) {
        const int c = f * 16 + col;
        float bv = BIAS ? bias[c] : 0.f;
#pragma unroll
        for (int j = 0; j < 4; ++j) {
            int rr = crow + j;
            if (rr < N) {
                float v = acc[f][j] + bv;
                if (OUT_BF16) ((ushort*)outv)[(size_t)rr * NC + c] = f2bf(v);
                else          ((float*)outv)[(size_t)rr * NC + c] = v;
            }
        }
    }
}

// ---------------------------------------------------------------------------
// fused aggregation on bf16 rows: out = relu(T[i] + sum_j T[j] + bias)
// F=128: half-wave (32 lanes x 8B) per node.
// ---------------------------------------------------------------------------
__global__ void agg_f128b_k(const ushort* __restrict__ T, const int* __restrict__ row_start,
                            const int* __restrict__ esrc, const float* __restrict__ bias,
                            ushort* __restrict__ out, int N) {
    const int hw = (blockIdx.x << 3) | (threadIdx.x >> 5);
    const int lane = threadIdx.x & 31;
    if (hw >= N) return;
    const uint2* T2 = (const uint2*)T;
    uint2 sv = T2[(size_t)hw * 32 + lane];
    float a0, a1, a2, a3;
    unpack2(sv.x, a0, a1);
    unpack2(sv.y, a2, a3);
    int p = row_start[hw];
    const int pe = row_start[hw + 1];
    for (; p + 3 < pe; p += 4) {
        int s0 = esrc[p], s1 = esrc[p + 1], s2 = esrc[p + 2], s3 = esrc[p + 3];
        uint2 v0 = T2[(size_t)s0 * 32 + lane];
        uint2 v1 = T2[(size_t)s1 * 32 + lane];
        uint2 v2 = T2[(size_t)s2 * 32 + lane];
        uint2 v3 = T2[(size_t)s3 * 32 + lane];
        float x0, x1, x2, x3;
        unpack2(v0.x, x0, x1); unpack2(v0.y, x2, x3);
        a0 += x0; a1 += x1; a2 += x2; a3 += x3;
        unpack2(v1.x, x0, x1); unpack2(v1.y, x2, x3);
        a0 += x0; a1 += x1; a2 += x2; a3 += x3;
        unpack2(v2.x, x0, x1); unpack2(v2.y, x2, x3);
        a0 += x0; a1 += x1; a2 += x2; a3 += x3;
        unpack2(v3.x, x0, x1); unpack2(v3.y, x2, x3);
        a0 += x0; a1 += x1; a2 += x2; a3 += x3;
    }
    for (; p < pe; ++p) {
        uint2 v = T2[(size_t)esrc[p] * 32 + lane];
        float x0, x1, x2, x3;
        unpack2(v.x, x0, x1); unpack2(v.y, x2, x3);
        a0 += x0; a1 += x1; a2 += x2; a3 += x3;
    }
    const float4 b = ((const float4*)bias)[lane];
    a0 = fmaxf(a0 + b.x, 0.f);
    a1 = fmaxf(a1 + b.y, 0.f);
    a2 = fmaxf(a2 + b.z, 0.f);
    a3 = fmaxf(a3 + b.w, 0.f);
    ((uint2*)out)[(size_t)hw * 32 + lane] = make_uint2(pack2(a0, a1), pack2(a2, a3));
}

// F=32: wave per node; 8 neighbor-groups x 8 lanes; cross-group shfl reduce.
__global__ void agg_f32b_k(const ushort* __restrict__ T, const int* __restrict__ row_start,
                           const int* __restrict__ esrc, const float* __restrict__ bias,
                           ushort* __restrict__ out, int N) {
    const int wid = (blockIdx.x << 2) | (threadIdx.x >> 6);
    const int lane = threadIdx.x & 63;
    const int g = lane >> 3, l8 = lane & 7;
    if (wid >= N) return;
    const uint2* T2 = (const uint2*)T;
    float a0 = 0.f, a1 = 0.f, a2 = 0.f, a3 = 0.f;
    const int p0 = row_start[wid];
    const int pe = row_start[wid + 1];
    for (int p = p0 + g; p < pe; p += 8) {
        uint2 v = T2[(size_t)esrc[p] * 8 + l8];
        float x0, x1, x2, x3;
        unpack2(v.x, x0, x1); unpack2(v.y, x2, x3);
        a0 += x0; a1 += x1; a2 += x2; a3 += x3;
    }
#pragma unroll
    for (int off = 8; off < 64; off <<= 1) {
        a0 += __shfl_xor(a0, off);
        a1 += __shfl_xor(a1, off);
        a2 += __shfl_xor(a2, off);
        a3 += __shfl_xor(a3, off);
    }
    if (g == 0) {
        uint2 sv = T2[(size_t)wid * 8 + l8];
        float s0, s1, s2, s3;
        unpack2(sv.x, s0, s1); unpack2(sv.y, s2, s3);
        const float4 b = ((const float4*)bias)[l8];
        a0 = fmaxf(a0 + s0 + b.x, 0.f);
        a1 = fmaxf(a1 + s1 + b.y, 0.f);
        a2 = fmaxf(a2 + s2 + b.z, 0.f);
        a3 = fmaxf(a3 + s3 + b.w, 0.f);
        ((uint2*)out)[(size_t)wid * 8 + l8] = make_uint2(pack2(a0, a1), pack2(a2, a3));
    }
}

// ---------------------------------------------------------------------------
// BatchNorm: column sums/sumsq (f32 input) -> scale/shift -> apply+relu
// ---------------------------------------------------------------------------
template <int F>
__global__ void stats_k(const float* __restrict__ U, int N, float* __restrict__ sums) {
    constexpr int RPB = 256 / F;
    const int tid = threadIdx.x;
    const int col = tid % F;
    const int rsub = tid / F;
    float s = 0.f, q = 0.f;
    for (int r = blockIdx.x * RPB + rsub; r < N; r += gridDim.x * RPB) {
        float v = U[(size_t)r * F + col];
        s += v;
        q += v * v;
    }
    __shared__ float ls[256], lq[256];
    ls[tid] = s; lq[tid] = q;
    __syncthreads();
    if (tid < F) {
#pragma unroll
        for (int k = 1; k < RPB; ++k) { s += ls[tid + k * F]; q += lq[tid + k * F]; }
        atomicAdd(&sums[col], s);
        atomicAdd(&sums[F + col], q);
    }
}

template <int F>
__global__ void finalize_k(const float* __restrict__ sums, const float* __restrict__ g,
                           const float* __restrict__ be, int N,
                           float* __restrict__ scale, float* __restrict__ shift) {
    const int c = threadIdx.x;
    if (c < F) {
        float inv_n = 1.f / (float)N;
        float mean = sums[c] * inv_n;
        float var = sums[F + c] * inv_n - mean * mean;
        float sc = g[c] * rsqrtf(var + BN_EPS);
        scale[c] = sc;
        shift[c] = be[c] - mean * sc;
    }
}

template <int F>
__global__ void bnapply_k(const float* __restrict__ U, const float* __restrict__ scale,
                          const float* __restrict__ shift, float* __restrict__ out, int total4) {
    const float4* U4 = (const float4*)U;
    const float4* S4 = (const float4*)scale;
    const float4* H4 = (const float4*)shift;
    float4* O4 = (float4*)out;
    const int stride = gridDim.x * blockDim.x;
    for (int i = blockIdx.x * blockDim.x + threadIdx.x; i < total4; i += stride) {
        int c4 = i % (F / 4);
        float4 u = U4[i], sc = S4[c4], sh = H4[c4];
        float4 o;
        o.x = fmaxf(u.x * sc.x + sh.x, 0.f);
        o.y = fmaxf(u.y * sc.y + sh.y, 0.f);
        o.z = fmaxf(u.z * sc.z + sh.z, 0.f);
        o.w = fmaxf(u.w * sc.w + sh.w, 0.f);
        O4[i] = o;
    }
}

template <int F>
__global__ void bnapply_bf_k(const float* __restrict__ U, const float* __restrict__ scale,
                             const float* __restrict__ shift, ushort* __restrict__ out,
                             int total4) {
    const float4* U4 = (const float4*)U;
    const float4* S4 = (const float4*)scale;
    const float4* H4 = (const float4*)shift;
    uint2* O2 = (uint2*)out;
    const int stride = gridDim.x * blockDim.x;
    for (int i = blockIdx.x * blockDim.x + threadIdx.x; i < total4; i += stride) {
        int c4 = i % (F / 4);
        float4 u = U4[i], sc = S4[c4], sh = H4[c4];
        float o0 = fmaxf(u.x * sc.x + sh.x, 0.f);
        float o1 = fmaxf(u.y * sc.y + sh.y, 0.f);
        float o2 = fmaxf(u.z * sc.z + sh.z, 0.f);
        float o3 = fmaxf(u.w * sc.w + sh.w, 0.f);
        O2[i] = make_uint2(pack2(o0, o1), pack2(o2, o3));
    }
}

// ---------------------------------------------------------------------------
extern "C" void kernel_launch(void* const* d_in, const int* in_sizes, int n_in,
                              void* d_out, int out_size, void* d_ws, size_t ws_size,
                              hipStream_t stream) {
    const float* x   = (const float*)d_in[0];
    const int*   eb  = (const int*)d_in[1];
    const float* W1a = (const float*)d_in[2];
    const float* b1a = (const float*)d_in[3];
    const float* W1b = (const float*)d_in[4];
    const float* b1b = (const float*)d_in[5];
    const float* g1  = (const float*)d_in[6];
    const float* be1 = (const float*)d_in[7];
    const float* W2a = (const float*)d_in[8];
    const float* b2a = (const float*)d_in[9];
    const float* W2b = (const float*)d_in[10];
    const float* b2b = (const float*)d_in[11];
    const float* g2  = (const float*)d_in[12];
    const float* be2 = (const float*)d_in[13];
    float* out = (float*)d_out;

    const int N = in_sizes[0] / F_IN;  // 100000
    const int E = in_sizes[1] / 2;     // 3200000
    const int NBUCK = (N + 511) >> BSHIFT;  // 196

    char* w = (char*)d_ws;
    size_t off = 0;
    auto alloc = [&](size_t bytes) -> void* {
        void* p = w + off;
        off = (off + bytes + 255) & ~(size_t)255;
        return p;
    };
    ushort* B0 = (ushort*)alloc((size_t)N * H1 * 2);    // s1b / t2b
    ushort* B1 = (ushort*)alloc((size_t)N * H1 * 2);    // t1b / h1b
    float*  B2 = (float*)alloc((size_t)N * H1 * 4);     // u1 -> {s2b, u2}
    ushort* s2b = (ushort*)B2;                          // N*H2 bf16
    float*  u2  = (float*)((char*)B2 + (size_t)N * H2 * 2);  // N*H2 f32, disjoint

    int* row_start = (int*)alloc((size_t)(N + 1) * 4);
    int* esrc      = (int*)alloc((size_t)E * 4);
    uint* rec      = (uint*)alloc((size_t)NBUCK * BCAP * 4);
    int* bucket_cursor = (int*)alloc(512 * 4);
    int* ebase     = (int*)alloc(513 * 4);
    int* flag      = (int*)alloc(256);
    ushort* w1aT = (ushort*)alloc(F_IN * H1 * 2);
    ushort* w1bT = (ushort*)alloc(H1 * H1 * 2);
    ushort* w2aT = (ushort*)alloc(H1 * H2 * 2);
    ushort* w2bT = (ushort*)alloc(H2 * H2 * 2);
    float* sums1 = (float*)alloc(2 * H1 * 4);
    float* sc1   = (float*)alloc(H1 * 4);
    float* sh1   = (float*)alloc(H1 * 4);
    float* sums2 = (float*)alloc(2 * H2 * 4);
    float* sc2   = (float*)alloc(H2 * 4);
    float* sh2   = (float*)alloc(H2 * 4);

    hipMemsetAsync(bucket_cursor, 0, 512 * 4, stream);
    hipMemsetAsync(sums1, 0, 2 * H1 * 4, stream);
    hipMemsetAsync(sums2, 0, 2 * H2 * 4, stream);

    // --- weight casts ---
    transpose_cast_k<<<(F_IN * H1 + 255) / 256, 256, 0, stream>>>(W1a, F_IN, H1, w1aT);
    transpose_cast_k<<<(H1 * H1 + 255) / 256, 256, 0, stream>>>(W1b, H1, H1, w1bT);
    transpose_cast_k<<<(H1 * H2 + 255) / 256, 256, 0, stream>>>(W2a, H1, H2, w2aT);
    transpose_cast_k<<<(H2 * H2 + 255) / 256, 256, 0, stream>>>(W2b, H2, H2, w2bT);

    // --- CSR build (two-level binning) ---
    detect_k<<<1, 128, 0, stream>>>(eb, flag);
    binA_k<<<256, 256, 0, stream>>>(eb, flag, E, N, NBUCK, bucket_cursor, rec);
    bscan_k<<<1, 64, 0, stream>>>(bucket_cursor, NBUCK, N, ebase, row_start);
    binB_k<<<NBUCK, 256, 0, stream>>>(rec, bucket_cursor, ebase, N, row_start, esrc);

    const int gemm_grid = (N + 63) / 64;

    // --- layer 1 ---
    // t1 = x @ W1a  (f32 A in-register cast; bf16 out, in B1)
    gemm_mfma_f32a_k<F_IN, H1, false, true><<<gemm_grid, 256, 0, stream>>>(x, w1aT, nullptr, B1, N);
    // s1 = relu(t1 + agg(t1) + b1a)  (bf16 out, in B0)
    agg_f128b_k<<<(N + 7) / 8, 256, 0, stream>>>(B1, row_start, esrc, b1a, B0, N);
    // u1 = s1 @ W1b + b1b  (f32 out, in B2)
    gemm_mfma_k<H1, H1, true, false><<<gemm_grid, 256, 0, stream>>>(B0, w1bT, b1b, B2, N);
    stats_k<H1><<<512, 256, 0, stream>>>(B2, N, sums1);
    finalize_k<H1><<<1, 128, 0, stream>>>(sums1, g1, be1, N, sc1, sh1);
    // h1 = relu(BN(u1))  (bf16 out, in B1)
    bnapply_bf_k<H1><<<12500, 256, 0, stream>>>(B2, sc1, sh1, B1, N * H1 / 4);

    // --- layer 2 ---
    // t2 = h1 @ W2a  (bf16 out, in B0)
    gemm_mfma_k<H1, H2, false, true><<<gemm_grid, 256, 0, stream>>>(B1, w2aT, nullptr, B0, N);
    // s2 = relu(t2 + agg(t2) + b2a)  (bf16 out, s2b in B2)
    agg_f32b_k<<<(N + 3) / 4, 256, 0, stream>>>(B0, row_start, esrc, b2a, s2b, N);
    // u2 = s2 @ W2b + b2b  (f32 out, u2 disjoint in B2)
    gemm_mfma_k<H2, H2, true, false><<<gemm_grid, 256, 0, stream>>>(s2b, w2bT, b2b, u2, N);
    stats_k<H2><<<512, 256, 0, stream>>>(u2, N, sums2);
    finalize_k<H2><<<1, 32, 0, stream>>>(sums2, g2, be2, N, sc2, sh2);
    bnapply_k<H2><<<3125, 256, 0, stream>>>(u2, sc2, sh2, out, N * H2 / 4);
}

// Round 5
// 426.762 us; speedup vs baseline: 2.9915x; 1.1899x over previous
//
#include <hip/hip_runtime.h>

#define F_IN 256
#define H1 128
#define H2 32
#define BN_EPS 1e-5f
#define BSHIFT 9
#define BCAP 32768
#define NSHARD 8

typedef short bf16x8 __attribute__((ext_vector_type(8)));
typedef float f32x4 __attribute__((ext_vector_type(4)));

__device__ __forceinline__ ushort f2bf(float f) {
    uint u = __float_as_uint(f);
    return (ushort)((u + 0x7FFFu + ((u >> 16) & 1u)) >> 16);
}
__device__ __forceinline__ float bf2f(ushort h) {
    return __uint_as_float((uint)h << 16);
}
__device__ __forceinline__ uint pack2(float a, float b) {
    return (uint)f2bf(a) | ((uint)f2bf(b) << 16);
}
__device__ __forceinline__ void unpack2(uint u, float& a, float& b) {
    a = __uint_as_float(u << 16);
    b = __uint_as_float(u & 0xFFFF0000u);
}

// ---------------------------------------------------------------------------
// edge_index dtype detection (int64 little-endian -> odd words all zero)
// ---------------------------------------------------------------------------
__global__ void detect_k(const int* __restrict__ eb, int* __restrict__ flag) {
    __shared__ int nz;
    if (threadIdx.x == 0) nz = 0;
    __syncthreads();
    if (eb[2 * threadIdx.x + 1] != 0) atomicAdd(&nz, 1);
    __syncthreads();
    if (threadIdx.x == 0) flag[0] = (nz == 0) ? 1 : 0;
}

__device__ __forceinline__ int clampN(int v, int N) {
    return v < 0 ? 0 : (v >= N ? N - 1 : v);
}

// ---------------------------------------------------------------------------
// CSR build. Phase A (single pass): chunk 4096 edges through LDS, per-chunk
// LDS histogram -> one global atomic per (chunk,bucket), grouped writes.
// ---------------------------------------------------------------------------
__global__ __launch_bounds__(256) void binA_k(const int* __restrict__ eb,
                                              const int* __restrict__ flag,
                                              int E, int N, int NBUCK,
                                              int* __restrict__ bucket_cursor,
                                              uint* __restrict__ rec) {
    __shared__ int lcnt[256];
    __shared__ int lbase[256];
    __shared__ uint lrec[4096];
    __shared__ ushort lbk[4096];
    __shared__ ushort lrk[4096];
    const int tid = threadIdx.x;
    const int is64 = flag[0];
    const int cbase = blockIdx.x * 4096;
    const int cnum = min(4096, E - cbase);
    if (cnum <= 0) return;
    for (int i = tid; i < NBUCK; i += 256) lcnt[i] = 0;
    __syncthreads();
    for (int i = tid; i < cnum; i += 256) {
        int e = cbase + i;
        int s = is64 ? eb[2 * e] : eb[e];
        int d = is64 ? eb[2 * (E + e)] : eb[E + e];
        s = clampN(s, N);
        d = clampN(d, N);
        int bk = d >> BSHIFT;
        int rk = atomicAdd(&lcnt[bk], 1);
        lrec[i] = (uint)s | ((uint)(d & 511) << 17);
        lbk[i] = (ushort)bk;
        lrk[i] = (ushort)rk;
    }
    __syncthreads();
    for (int i = tid; i < NBUCK; i += 256)
        lbase[i] = atomicAdd(&bucket_cursor[i], lcnt[i]);
    __syncthreads();
    for (int i = tid; i < cnum; i += 256) {
        int bk = lbk[i];
        int pos = lbase[bk] + lrk[i];
        if (pos < BCAP) rec[(size_t)bk * BCAP + pos] = lrec[i];
    }
}

// exclusive scan over bucket counts
__global__ void bscan_k(const int* __restrict__ bucket_cursor, int NBUCK, int N,
                        int* __restrict__ ebase, int* __restrict__ row_start) {
    if (threadIdx.x == 0 && blockIdx.x == 0) {
        int acc = 0;
        for (int i = 0; i < NBUCK; ++i) {
            ebase[i] = acc;
            int c = bucket_cursor[i];
            acc += (c < BCAP) ? c : BCAP;
        }
        ebase[NBUCK] = acc;
        row_start[N] = acc;
    }
}

// Phase B: one block per bucket; LDS histogram + scan -> row_start + esrc.
__global__ __launch_bounds__(256) void binB_k(const uint* __restrict__ rec,
                                              const int* __restrict__ bucket_cursor,
                                              const int* __restrict__ ebase,
                                              int N, int* __restrict__ row_start,
                                              int* __restrict__ esrc) {
    __shared__ int cntA[512];
    __shared__ int cntB[512];
    const int bk = blockIdx.x;
    const int tid = threadIdx.x;
    int cnt = bucket_cursor[bk];
    if (cnt > BCAP) cnt = BCAP;
    const uint* r = rec + (size_t)bk * BCAP;
    const int base = ebase[bk];
    for (int i = tid; i < 512; i += 256) cntA[i] = 0;
    __syncthreads();
    for (int i = tid; i < cnt; i += 256) atomicAdd(&cntA[r[i] >> 17], 1);
    __syncthreads();
    int* src = cntA;
    int* dst = cntB;
    for (int off = 1; off < 512; off <<= 1) {
        for (int i = tid; i < 512; i += 256)
            dst[i] = src[i] + (i >= off ? src[i - off] : 0);
        __syncthreads();
        int* t = src; src = dst; dst = t;
    }
    const int n0 = bk << BSHIFT;
    for (int i = tid; i < 512; i += 256) {
        int node = n0 + i;
        if (node < N) row_start[node] = base + (i ? src[i - 1] : 0);
    }
    for (int i = tid; i < 512; i += 256) dst[i] = 0;
    __syncthreads();
    for (int i = tid; i < cnt; i += 256) {
        uint rv = r[i];
        int dl = rv >> 17;
        int rank = atomicAdd(&dst[dl], 1);
        esrc[base + (dl ? src[dl - 1] : 0) + rank] = (int)(rv & 0x1FFFFu);
    }
}

// ---------------------------------------------------------------------------
// merged weight transpose+cast: W[K][NC] f32 -> WT[NC][K] bf16 (all 4)
// ---------------------------------------------------------------------------
__global__ void wcast_k(const float* __restrict__ W1a, const float* __restrict__ W1b,
                        const float* __restrict__ W2a, const float* __restrict__ W2b,
                        ushort* __restrict__ w1aT, ushort* __restrict__ w1bT,
                        ushort* __restrict__ w2aT, ushort* __restrict__ w2bT) {
    int idx = blockIdx.x * 256 + threadIdx.x;
    if (idx < 32768) {                // 256x128
        int k = idx >> 7, c = idx & 127;
        w1aT[c * 256 + k] = f2bf(W1a[idx]);
    } else if (idx < 49152) {         // 128x128
        int t = idx - 32768;
        int k = t >> 7, c = t & 127;
        w1bT[c * 128 + k] = f2bf(W1b[t]);
    } else if (idx < 53248) {         // 128x32
        int t = idx - 49152;
        int k = t >> 5, c = t & 31;
        w2aT[c * 128 + k] = f2bf(W2a[t]);
    } else if (idx < 54272) {         // 32x32
        int t = idx - 53248;
        int k = t >> 5, c = t & 31;
        w2bT[c * 32 + k] = f2bf(W2b[t]);
    }
}

// ---------------------------------------------------------------------------
// shared GEMM epilogue: store + optional fused column stats
// ---------------------------------------------------------------------------
template <int NC, bool BIAS, bool OUT_BF16, bool STATS, int NF>
__device__ __forceinline__ void gemm_epilogue(f32x4* acc, const float* bias,
                                              void* outv, int N, int row0,
                                              int lane, float* sums) {
    __shared__ float ssum[NC];
    __shared__ float ssq[NC];
    if (STATS) {
        if (threadIdx.x < NC) { ssum[threadIdx.x] = 0.f; ssq[threadIdx.x] = 0.f; }
        __syncthreads();
    }
    const int col0 = lane & 15;
    const int crow = row0 + (lane >> 4) * 4;
#pragma unroll
    for (int f = 0; f < NF; ++f) {
        const int c = f * 16 + col0;
        float bv = BIAS ? bias[c] : 0.f;
        float sv = 0.f, qv = 0.f;
#pragma unroll
        for (int j = 0; j < 4; ++j) {
            int rr = crow + j;
            if (rr < N) {
                float v = acc[f][j] + bv;
                if (OUT_BF16) ((ushort*)outv)[(size_t)rr * NC + c] = f2bf(v);
                else          ((float*)outv)[(size_t)rr * NC + c] = v;
                if (STATS) { sv += v; qv += v * v; }
            }
        }
        if (STATS) {
            sv += __shfl_xor(sv, 16); sv += __shfl_xor(sv, 32);
            qv += __shfl_xor(qv, 16); qv += __shfl_xor(qv, 32);
            if ((lane >> 4) == 0) {
                atomicAdd(&ssum[c], sv);
                atomicAdd(&ssq[c], qv);
            }
        }
    }
    if (STATS) {
        __syncthreads();
        if (threadIdx.x < NC) {
            float* sh = sums + (blockIdx.x & (NSHARD - 1)) * 2 * NC;
            atomicAdd(&sh[threadIdx.x], ssum[threadIdx.x]);
            atomicAdd(&sh[NC + threadIdx.x], ssq[threadIdx.x]);
        }
    }
}

// MFMA GEMM, bf16 A: out[N,NC] = A[N,K] @ WT[NC,K]^T (+bias) [+col stats]
template <int K, int NC, bool BIAS, bool OUT_BF16, bool STATS>
__global__ __launch_bounds__(256) void gemm_mfma_k(const ushort* __restrict__ A,
                                                   const ushort* __restrict__ WT,
                                                   const float* __restrict__ bias,
                                                   void* __restrict__ outv, int N,
                                                   float* __restrict__ sums) {
    constexpr int NF = NC / 16;
    const int lane = threadIdx.x & 63;
    const int wave = threadIdx.x >> 6;
    const int row0 = blockIdx.x * 64 + wave * 16;
    const int col = lane & 15;
    const int k0 = (lane >> 4) * 8;
    int arow = row0 + col;
    if (arow >= N) arow = N - 1;

    f32x4 acc[NF];
#pragma unroll
    for (int f = 0; f < NF; ++f) acc[f] = (f32x4){0.f, 0.f, 0.f, 0.f};
#pragma unroll
    for (int kc = 0; kc < K; kc += 32) {
        bf16x8 af = *(const bf16x8*)&A[(size_t)arow * K + kc + k0];
#pragma unroll
        for (int f = 0; f < NF; ++f) {
            bf16x8 bf = *(const bf16x8*)&WT[(size_t)(f * 16 + col) * K + kc + k0];
            acc[f] = __builtin_amdgcn_mfma_f32_16x16x32_bf16(af, bf, acc[f], 0, 0, 0);
        }
    }
    gemm_epilogue<NC, BIAS, OUT_BF16, STATS, NF>(acc, bias, outv, N, row0, lane, sums);
}

// MFMA GEMM, f32 A packed in-register (layer-1 first GEMM)
template <int K, int NC, bool OUT_BF16>
__global__ __launch_bounds__(256) void gemm_mfma_f32a_k(const float* __restrict__ Af,
                                                        const ushort* __restrict__ WT,
                                                        void* __restrict__ outv, int N) {
    constexpr int NF = NC / 16;
    const int lane = threadIdx.x & 63;
    const int wave = threadIdx.x >> 6;
    const int row0 = blockIdx.x * 64 + wave * 16;
    const int col = lane & 15;
    const int k0 = (lane >> 4) * 8;
    int arow = row0 + col;
    if (arow >= N) arow = N - 1;

    f32x4 acc[NF];
#pragma unroll
    for (int f = 0; f < NF; ++f) acc[f] = (f32x4){0.f, 0.f, 0.f, 0.f};
#pragma unroll
    for (int kc = 0; kc < K; kc += 32) {
        const float* ap = &Af[(size_t)arow * K + kc + k0];
        float4 p = *(const float4*)ap;
        float4 q = *(const float4*)(ap + 4);
        bf16x8 af;
        af[0] = (short)f2bf(p.x); af[1] = (short)f2bf(p.y);
        af[2] = (short)f2bf(p.z); af[3] = (short)f2bf(p.w);
        af[4] = (short)f2bf(q.x); af[5] = (short)f2bf(q.y);
        af[6] = (short)f2bf(q.z); af[7] = (short)f2bf(q.w);
#pragma unroll
        for (int f = 0; f < NF; ++f) {
            bf16x8 bf = *(const bf16x8*)&WT[(size_t)(f * 16 + col) * K + kc + k0];
            acc[f] = __builtin_amdgcn_mfma_f32_16x16x32_bf16(af, bf, acc[f], 0, 0, 0);
        }
    }
    gemm_epilogue<NC, false, OUT_BF16, false, NF>(acc, nullptr, outv, N, row0, lane, nullptr);
}

// MFMA GEMM with fused BN-apply+ReLU on A: A_eff[r][k] = relu(u[r][k]*sc[k]+sh[k])
template <int K, int NC, bool OUT_BF16>
__global__ __launch_bounds__(256) void gemm_mfma_bnA_k(const ushort* __restrict__ U,
                                                       const ushort* __restrict__ WT,
                                                       const float* __restrict__ sc,
                                                       const float* __restrict__ sh,
                                                       void* __restrict__ outv, int N) {
    constexpr int NF = NC / 16;
    const int lane = threadIdx.x & 63;
    const int wave = threadIdx.x >> 6;
    const int row0 = blockIdx.x * 64 + wave * 16;
    const int col = lane & 15;
    const int k0 = (lane >> 4) * 8;
    int arow = row0 + col;
    if (arow >= N) arow = N - 1;

    f32x4 acc[NF];
#pragma unroll
    for (int f = 0; f < NF; ++f) acc[f] = (f32x4){0.f, 0.f, 0.f, 0.f};
#pragma unroll
    for (int kc = 0; kc < K; kc += 32) {
        bf16x8 raw = *(const bf16x8*)&U[(size_t)arow * K + kc + k0];
        float4 c0 = *(const float4*)&sc[kc + k0];
        float4 c1 = *(const float4*)&sc[kc + k0 + 4];
        float4 h0 = *(const float4*)&sh[kc + k0];
        float4 h1 = *(const float4*)&sh[kc + k0 + 4];
        bf16x8 af;
        af[0] = (short)f2bf(fmaxf(bf2f((ushort)raw[0]) * c0.x + h0.x, 0.f));
        af[1] = (short)f2bf(fmaxf(bf2f((ushort)raw[1]) * c0.y + h0.y, 0.f));
        af[2] = (short)f2bf(fmaxf(bf2f((ushort)raw[2]) * c0.z + h0.z, 0.f));
        af[3] = (short)f2bf(fmaxf(bf2f((ushort)raw[3]) * c0.w + h0.w, 0.f));
        af[4] = (short)f2bf(fmaxf(bf2f((ushort)raw[4]) * c1.x + h1.x, 0.f));
        af[5] = (short)f2bf(fmaxf(bf2f((ushort)raw[5]) * c1.y + h1.y, 0.f));
        af[6] = (short)f2bf(fmaxf(bf2f((ushort)raw[6]) * c1.z + h1.z, 0.f));
        af[7] = (short)f2bf(fmaxf(bf2f((ushort)raw[7]) * c1.w + h1.w, 0.f));
#pragma unroll
        for (int f = 0; f < NF; ++f) {
            bf16x8 bf = *(const bf16x8*)&WT[(size_t)(f * 16 + col) * K + kc + k0];
            acc[f] = __builtin_amdgcn_mfma_f32_16x16x32_bf16(af, bf, acc[f], 0, 0, 0);
        }
    }
    gemm_epilogue<NC, false, OUT_BF16, false, NF>(acc, nullptr, outv, N, row0, lane, nullptr);
}

// ---------------------------------------------------------------------------
// fused aggregation on bf16 rows: out = relu(T[i] + sum_j T[j] + bias)
// ---------------------------------------------------------------------------
__global__ void agg_f128b_k(const ushort* __restrict__ T, const int* __restrict__ row_start,
                            const int* __restrict__ esrc, const float* __restrict__ bias,
                            ushort* __restrict__ out, int N) {
    const int hw = (blockIdx.x << 3) | (threadIdx.x >> 5);
    const int lane = threadIdx.x & 31;
    if (hw >= N) return;
    const uint2* T2 = (const uint2*)T;
    uint2 sv = T2[(size_t)hw * 32 + lane];
    float a0, a1, a2, a3;
    unpack2(sv.x, a0, a1);
    unpack2(sv.y, a2, a3);
    int p = row_start[hw];
    const int pe = row_start[hw + 1];
    for (; p + 3 < pe; p += 4) {
        int s0 = esrc[p], s1 = esrc[p + 1], s2 = esrc[p + 2], s3 = esrc[p + 3];
        uint2 v0 = T2[(size_t)s0 * 32 + lane];
        uint2 v1 = T2[(size_t)s1 * 32 + lane];
        uint2 v2 = T2[(size_t)s2 * 32 + lane];
        uint2 v3 = T2[(size_t)s3 * 32 + lane];
        float x0, x1, x2, x3;
        unpack2(v0.x, x0, x1); unpack2(v0.y, x2, x3);
        a0 += x0; a1 += x1; a2 += x2; a3 += x3;
        unpack2(v1.x, x0, x1); unpack2(v1.y, x2, x3);
        a0 += x0; a1 += x1; a2 += x2; a3 += x3;
        unpack2(v2.x, x0, x1); unpack2(v2.y, x2, x3);
        a0 += x0; a1 += x1; a2 += x2; a3 += x3;
        unpack2(v3.x, x0, x1); unpack2(v3.y, x2, x3);
        a0 += x0; a1 += x1; a2 += x2; a3 += x3;
    }
    for (; p < pe; ++p) {
        uint2 v = T2[(size_t)esrc[p] * 32 + lane];
        float x0, x1, x2, x3;
        unpack2(v.x, x0, x1); unpack2(v.y, x2, x3);
        a0 += x0; a1 += x1; a2 += x2; a3 += x3;
    }
    const float4 b = ((const float4*)bias)[lane];
    a0 = fmaxf(a0 + b.x, 0.f);
    a1 = fmaxf(a1 + b.y, 0.f);
    a2 = fmaxf(a2 + b.z, 0.f);
    a3 = fmaxf(a3 + b.w, 0.f);
    ((uint2*)out)[(size_t)hw * 32 + lane] = make_uint2(pack2(a0, a1), pack2(a2, a3));
}

__global__ void agg_f32b_k(const ushort* __restrict__ T, const int* __restrict__ row_start,
                           const int* __restrict__ esrc, const float* __restrict__ bias,
                           ushort* __restrict__ out, int N) {
    const int wid = (blockIdx.x << 2) | (threadIdx.x >> 6);
    const int lane = threadIdx.x & 63;
    const int g = lane >> 3, l8 = lane & 7;
    if (wid >= N) return;
    const uint2* T2 = (const uint2*)T;
    float a0 = 0.f, a1 = 0.f, a2 = 0.f, a3 = 0.f;
    const int p0 = row_start[wid];
    const int pe = row_start[wid + 1];
    for (int p = p0 + g; p < pe; p += 8) {
        uint2 v = T2[(size_t)esrc[p] * 8 + l8];
        float x0, x1, x2, x3;
        unpack2(v.x, x0, x1); unpack2(v.y, x2, x3);
        a0 += x0; a1 += x1; a2 += x2; a3 += x3;
    }
#pragma unroll
    for (int off = 8; off < 64; off <<= 1) {
        a0 += __shfl_xor(a0, off);
        a1 += __shfl_xor(a1, off);
        a2 += __shfl_xor(a2, off);
        a3 += __shfl_xor(a3, off);
    }
    if (g == 0) {
        uint2 sv = T2[(size_t)wid * 8 + l8];
        float s0, s1, s2, s3;
        unpack2(sv.x, s0, s1); unpack2(sv.y, s2, s3);
        const float4 b = ((const float4*)bias)[l8];
        a0 = fmaxf(a0 + s0 + b.x, 0.f);
        a1 = fmaxf(a1 + s1 + b.y, 0.f);
        a2 = fmaxf(a2 + s2 + b.z, 0.f);
        a3 = fmaxf(a3 + s3 + b.w, 0.f);
        ((uint2*)out)[(size_t)wid * 8 + l8] = make_uint2(pack2(a0, a1), pack2(a2, a3));
    }
}

// ---------------------------------------------------------------------------
// BN finalize (reads NSHARD sharded sums) + final apply
// ---------------------------------------------------------------------------
template <int F>
__global__ void finalize_k(const float* __restrict__ sums, const float* __restrict__ g,
                           const float* __restrict__ be, int N,
                           float* __restrict__ scale, float* __restrict__ shift) {
    const int c = threadIdx.x;
    if (c < F) {
        float s = 0.f, q = 0.f;
        for (int sh = 0; sh < NSHARD; ++sh) {
            s += sums[sh * 2 * F + c];
            q += sums[sh * 2 * F + F + c];
        }
        float inv_n = 1.f / (float)N;
        float mean = s * inv_n;
        float var = q * inv_n - mean * mean;
        float sc = g[c] * rsqrtf(var + BN_EPS);
        scale[c] = sc;
        shift[c] = be[c] - mean * sc;
    }
}

template <int F>
__global__ void bnapply_k(const float* __restrict__ U, const float* __restrict__ scale,
                          const float* __restrict__ shift, float* __restrict__ out, int total4) {
    const float4* U4 = (const float4*)U;
    const float4* S4 = (const float4*)scale;
    const float4* H4 = (const float4*)shift;
    float4* O4 = (float4*)out;
    const int stride = gridDim.x * blockDim.x;
    for (int i = blockIdx.x * blockDim.x + threadIdx.x; i < total4; i += stride) {
        int c4 = i % (F / 4);
        float4 u = U4[i], sc = S4[c4], sh = H4[c4];
        float4 o;
        o.x = fmaxf(u.x * sc.x + sh.x, 0.f);
        o.y = fmaxf(u.y * sc.y + sh.y, 0.f);
        o.z = fmaxf(u.z * sc.z + sh.z, 0.f);
        o.w = fmaxf(u.w * sc.w + sh.w, 0.f);
        O4[i] = o;
    }
}

// ---------------------------------------------------------------------------
extern "C" void kernel_launch(void* const* d_in, const int* in_sizes, int n_in,
                              void* d_out, int out_size, void* d_ws, size_t ws_size,
                              hipStream_t stream) {
    const float* x   = (const float*)d_in[0];
    const int*   eb  = (const int*)d_in[1];
    const float* W1a = (const float*)d_in[2];
    const float* b1a = (const float*)d_in[3];
    const float* W1b = (const float*)d_in[4];
    const float* b1b = (const float*)d_in[5];
    const float* g1  = (const float*)d_in[6];
    const float* be1 = (const float*)d_in[7];
    const float* W2a = (const float*)d_in[8];
    const float* b2a = (const float*)d_in[9];
    const float* W2b = (const float*)d_in[10];
    const float* b2b = (const float*)d_in[11];
    const float* g2  = (const float*)d_in[12];
    const float* be2 = (const float*)d_in[13];
    float* out = (float*)d_out;

    const int N = in_sizes[0] / F_IN;  // 100000
    const int E = in_sizes[1] / 2;     // 3200000
    const int NBUCK = (N + 511) >> BSHIFT;  // 196

    char* w = (char*)d_ws;
    size_t off = 0;
    auto alloc = [&](size_t bytes) -> void* {
        void* p = w + off;
        off = (off + bytes + 255) & ~(size_t)255;
        return p;
    };
    ushort* B0 = (ushort*)alloc((size_t)N * H1 * 2);  // s1b -> s2b
    ushort* B1 = (ushort*)alloc((size_t)N * H1 * 2);  // t1b -> t2b
    char*   B2 = (char*)alloc((size_t)N * H1 * 4);    // u1b (bf16) -> u2 (f32)
    ushort* u1b = (ushort*)B2;
    float*  u2  = (float*)B2;

    int* row_start = (int*)alloc((size_t)(N + 1) * 4);
    int* esrc      = (int*)alloc((size_t)E * 4);
    uint* rec      = (uint*)alloc((size_t)NBUCK * BCAP * 4);
    int* bucket_cursor = (int*)alloc(512 * 4);
    int* ebase     = (int*)alloc(513 * 4);
    int* flag      = (int*)alloc(256);
    ushort* w1aT = (ushort*)alloc(F_IN * H1 * 2);
    ushort* w1bT = (ushort*)alloc(H1 * H1 * 2);
    ushort* w2aT = (ushort*)alloc(H1 * H2 * 2);
    ushort* w2bT = (ushort*)alloc(H2 * H2 * 2);
    float* sums1 = (float*)alloc(NSHARD * 2 * H1 * 4);
    float* sc1   = (float*)alloc(H1 * 4);
    float* sh1   = (float*)alloc(H1 * 4);
    float* sums2 = (float*)alloc(NSHARD * 2 * H2 * 4);
    float* sc2   = (float*)alloc(H2 * 4);
    float* sh2   = (float*)alloc(H2 * 4);

    hipMemsetAsync(bucket_cursor, 0, 512 * 4, stream);
    hipMemsetAsync(sums1, 0, NSHARD * 2 * H1 * 4, stream);
    hipMemsetAsync(sums2, 0, NSHARD * 2 * H2 * 4, stream);

    // --- weight casts (merged) ---
    wcast_k<<<213, 256, 0, stream>>>(W1a, W1b, W2a, W2b, w1aT, w1bT, w2aT, w2bT);

    // --- CSR build ---
    detect_k<<<1, 128, 0, stream>>>(eb, flag);
    binA_k<<<(E + 4095) / 4096, 256, 0, stream>>>(eb, flag, E, N, NBUCK, bucket_cursor, rec);
    bscan_k<<<1, 64, 0, stream>>>(bucket_cursor, NBUCK, N, ebase, row_start);
    binB_k<<<NBUCK, 256, 0, stream>>>(rec, bucket_cursor, ebase, N, row_start, esrc);

    const int gemm_grid = (N + 63) / 64;

    // --- layer 1 ---
    // t1 = x @ W1a (bf16 out)
    gemm_mfma_f32a_k<F_IN, H1, true><<<gemm_grid, 256, 0, stream>>>(x, w1aT, B1, N);
    // s1 = relu(t1 + agg(t1) + b1a)
    agg_f128b_k<<<(N + 7) / 8, 256, 0, stream>>>(B1, row_start, esrc, b1a, B0, N);
    // u1 = s1 @ W1b + b1b (bf16 out) + fused column stats
    gemm_mfma_k<H1, H1, true, true, true><<<gemm_grid, 256, 0, stream>>>(B0, w1bT, b1b, u1b, N, sums1);
    finalize_k<H1><<<1, 128, 0, stream>>>(sums1, g1, be1, N, sc1, sh1);
    // t2 = relu(BN(u1)) @ W2a  (BN-apply fused into A-load; bf16 out)
    gemm_mfma_bnA_k<H1, H2, true><<<gemm_grid, 256, 0, stream>>>(u1b, w2aT, sc1, sh1, B1, N);

    // --- layer 2 ---
    // s2 = relu(t2 + agg(t2) + b2a)
    agg_f32b_k<<<(N + 3) / 4, 256, 0, stream>>>(B1, row_start, esrc, b2a, B0, N);
    // u2 = s2 @ W2b + b2b (f32 out) + fused column stats
    gemm_mfma_k<H2, H2, true, false, true><<<gemm_grid, 256, 0, stream>>>(B0, w2bT, b2b, u2, N, sums2);
    finalize_k<H2><<<1, 32, 0, stream>>>(sums2, g2, be2, N, sc2, sh2);
    bnapply_k<H2><<<3125, 256, 0, stream>>>(u2, sc2, sh2, out, N * H2 / 4);
}

// Round 6
// 387.218 us; speedup vs baseline: 3.2970x; 1.1021x over previous
//
#include <hip/hip_runtime.h>

#define F_IN 256
#define H1 128
#define H2 32
#define BN_EPS 1e-5f
#define BSHIFT 8
#define BCAP 16384
#define CHUNK 2048
#define NSHARD 8

typedef short bf16x8 __attribute__((ext_vector_type(8)));
typedef float f32x4 __attribute__((ext_vector_type(4)));

__device__ __forceinline__ ushort f2bf(float f) {
    uint u = __float_as_uint(f);
    return (ushort)((u + 0x7FFFu + ((u >> 16) & 1u)) >> 16);
}
__device__ __forceinline__ float bf2f(ushort h) {
    return __uint_as_float((uint)h << 16);
}
__device__ __forceinline__ uint pack2(float a, float b) {
    return (uint)f2bf(a) | ((uint)f2bf(b) << 16);
}
__device__ __forceinline__ void unpack2(uint u, float& a, float& b) {
    a = __uint_as_float(u << 16);
    b = __uint_as_float(u & 0xFFFF0000u);
}
__device__ __forceinline__ int clampN(int v, int N) {
    return v < 0 ? 0 : (v >= N ? N - 1 : v);
}

// ---------------------------------------------------------------------------
// super0: weight transpose+cast (blocks 0..211) + zero scratch (block 212)
// ---------------------------------------------------------------------------
__global__ __launch_bounds__(256) void super0_k(
    const float* __restrict__ W1a, const float* __restrict__ W1b,
    const float* __restrict__ W2a, const float* __restrict__ W2b,
    ushort* __restrict__ w1aT, ushort* __restrict__ w1bT,
    ushort* __restrict__ w2aT, ushort* __restrict__ w2bT,
    int* __restrict__ bucket_cursor, float* __restrict__ sums1,
    float* __restrict__ sums2) {
    const int tid = threadIdx.x;
    if (blockIdx.x == 212) {
        for (int i = tid; i < 512; i += 256) bucket_cursor[i] = 0;
        for (int i = tid; i < NSHARD * 2 * H1; i += 256) sums1[i] = 0.f;
        for (int i = tid; i < NSHARD * 2 * H2; i += 256) sums2[i] = 0.f;
        return;
    }
    int idx = blockIdx.x * 256 + tid;
    if (idx < 32768) {                // 256x128
        int k = idx >> 7, c = idx & 127;
        w1aT[c * 256 + k] = f2bf(W1a[idx]);
    } else if (idx < 49152) {         // 128x128
        int t = idx - 32768;
        int k = t >> 7, c = t & 127;
        w1bT[c * 128 + k] = f2bf(W1b[t]);
    } else if (idx < 53248) {         // 128x32
        int t = idx - 49152;
        int k = t >> 5, c = t & 31;
        w2aT[c * 128 + k] = f2bf(W2a[t]);
    } else if (idx < 54272) {         // 32x32
        int t = idx - 53248;
        int k = t >> 5, c = t & 31;
        w2bT[c * 32 + k] = f2bf(W2b[t]);
    }
}

// ---------------------------------------------------------------------------
// binA body: chunk CHUNK edges through LDS, per-chunk histogram -> one global
// atomic per (chunk,bucket), grouped record writes. Self-detects int64.
// ---------------------------------------------------------------------------
__device__ __forceinline__ void binA_body(int bid, const int* __restrict__ eb,
                                          int E, int N, int NBUCK,
                                          int* __restrict__ bucket_cursor,
                                          uint* __restrict__ rec) {
    __shared__ int lcnt[512];
    __shared__ int lbase[512];
    __shared__ uint lrec[CHUNK];
    __shared__ ushort lbk[CHUNK];
    __shared__ ushort lrk[CHUNK];
    __shared__ int nzf;
    const int tid = threadIdx.x;
    const int cbase = bid * CHUNK;
    const int cnum = min(CHUNK, E - cbase);
    if (cnum <= 0) return;
    if (tid == 0) nzf = 0;
    __syncthreads();
    {   // sample odd words of this chunk: int64 -> all high halves zero
        int i = tid * (CHUNK / 256);
        if (i < cnum && eb[2 * (cbase + i) + 1] != 0) atomicAdd(&nzf, 1);
    }
    for (int i = tid; i < NBUCK; i += 256) lcnt[i] = 0;
    __syncthreads();
    const int is64 = (nzf == 0);
    for (int i = tid; i < cnum; i += 256) {
        int e = cbase + i;
        int s = is64 ? eb[2 * e] : eb[e];
        int d = is64 ? eb[2 * (E + e)] : eb[E + e];
        s = clampN(s, N);
        d = clampN(d, N);
        int bk = d >> BSHIFT;
        int rk = atomicAdd(&lcnt[bk], 1);
        lrec[i] = (uint)s | ((uint)(d & 255) << 17);
        lbk[i] = (ushort)bk;
        lrk[i] = (ushort)rk;
    }
    __syncthreads();
    for (int i = tid; i < NBUCK; i += 256)
        lbase[i] = atomicAdd(&bucket_cursor[i], lcnt[i]);
    __syncthreads();
    for (int i = tid; i < cnum; i += 256) {
        int bk = lbk[i];
        int pos = lbase[bk] + lrk[i];
        if (pos < BCAP) rec[(size_t)bk * BCAP + pos] = lrec[i];
    }
}

// ---------------------------------------------------------------------------
// gemm1 body: t1 = x(f32, packed in-register) @ W1aT, bf16 out
// ---------------------------------------------------------------------------
__device__ __forceinline__ void gemm1_body(int bid, const float* __restrict__ Af,
                                           const ushort* __restrict__ WT,
                                           ushort* __restrict__ outb, int N) {
    constexpr int K = F_IN, NC = H1, NF = NC / 16;
    const int lane = threadIdx.x & 63;
    const int wave = threadIdx.x >> 6;
    const int row0 = bid * 64 + wave * 16;
    const int col = lane & 15;
    const int k0 = (lane >> 4) * 8;
    int arow = row0 + col;
    if (arow >= N) arow = N - 1;

    f32x4 acc[NF];
#pragma unroll
    for (int f = 0; f < NF; ++f) acc[f] = (f32x4){0.f, 0.f, 0.f, 0.f};
#pragma unroll
    for (int kc = 0; kc < K; kc += 32) {
        const float* ap = &Af[(size_t)arow * K + kc + k0];
        float4 p = *(const float4*)ap;
        float4 q = *(const float4*)(ap + 4);
        bf16x8 af;
        af[0] = (short)f2bf(p.x); af[1] = (short)f2bf(p.y);
        af[2] = (short)f2bf(p.z); af[3] = (short)f2bf(p.w);
        af[4] = (short)f2bf(q.x); af[5] = (short)f2bf(q.y);
        af[6] = (short)f2bf(q.z); af[7] = (short)f2bf(q.w);
#pragma unroll
        for (int f = 0; f < NF; ++f) {
            bf16x8 bf = *(const bf16x8*)&WT[(size_t)(f * 16 + col) * K + kc + k0];
            acc[f] = __builtin_amdgcn_mfma_f32_16x16x32_bf16(af, bf, acc[f], 0, 0, 0);
        }
    }
    const int crow = row0 + (lane >> 4) * 4;
#pragma unroll
    for (int f = 0; f < NF; ++f) {
        const int c = f * 16 + col;
#pragma unroll
        for (int j = 0; j < 4; ++j) {
            int rr = crow + j;
            if (rr < N) outb[(size_t)rr * NC + c] = f2bf(acc[f][j]);
        }
    }
}

// super1: binA blocks [0, GB) overlap gemm1 blocks [GB, GB+G1)
__global__ __launch_bounds__(256) void super1_k(
    const int* __restrict__ eb, int E, int N, int NBUCK, int GB,
    int* __restrict__ bucket_cursor, uint* __restrict__ rec,
    const float* __restrict__ x, const ushort* __restrict__ w1aT,
    ushort* __restrict__ t1b) {
    if ((int)blockIdx.x < GB)
        binA_body(blockIdx.x, eb, E, N, NBUCK, bucket_cursor, rec);
    else
        gemm1_body(blockIdx.x - GB, x, w1aT, t1b, N);
}

// ---------------------------------------------------------------------------
// binB: one block per bucket; self-computed prefix base (bscan folded in);
// LDS histogram + scan -> row_start + esrc.
// ---------------------------------------------------------------------------
__global__ __launch_bounds__(256) void binB_k(const uint* __restrict__ rec,
                                              const int* __restrict__ bucket_cursor,
                                              int N, int NBUCK,
                                              int* __restrict__ row_start,
                                              int* __restrict__ esrc) {
    __shared__ int cntA[256];
    __shared__ int cntB[256];
    __shared__ int red[256];
    const int bk = blockIdx.x;
    const int tid = threadIdx.x;
    // prefix base over previous buckets
    int part = 0;
    for (int i = tid; i < bk; i += 256) {
        int c = bucket_cursor[i];
        part += (c < BCAP) ? c : BCAP;
    }
    red[tid] = part;
    __syncthreads();
    for (int s = 128; s > 0; s >>= 1) {
        if (tid < s) red[tid] += red[tid + s];
        __syncthreads();
    }
    const int base = red[0];
    int cnt = bucket_cursor[bk];
    if (cnt > BCAP) cnt = BCAP;
    if (bk == NBUCK - 1 && tid == 0) row_start[N] = base + cnt;

    const uint* r = rec + (size_t)bk * BCAP;
    cntA[tid] = 0;
    __syncthreads();
    for (int i = tid; i < cnt; i += 256) atomicAdd(&cntA[r[i] >> 17], 1);
    __syncthreads();
    int* src = cntA;
    int* dst = cntB;
    for (int off = 1; off < 256; off <<= 1) {
        int v = src[tid] + (tid >= off ? src[tid - off] : 0);
        __syncthreads();
        dst[tid] = v;
        __syncthreads();
        int* t = src; src = dst; dst = t;
    }
    const int n0 = bk << BSHIFT;
    {
        int node = n0 + tid;
        if (node < N) row_start[node] = base + (tid ? src[tid - 1] : 0);
    }
    dst[tid] = 0;
    __syncthreads();
    for (int i = tid; i < cnt; i += 256) {
        uint rv = r[i];
        int dl = rv >> 17;
        int rank = atomicAdd(&dst[dl], 1);
        esrc[base + (dl ? src[dl - 1] : 0) + rank] = (int)(rv & 0x1FFFFu);
    }
}

// ---------------------------------------------------------------------------
// shared GEMM epilogue: store + optional fused column stats
// ---------------------------------------------------------------------------
template <int NC, bool BIAS, bool OUT_BF16, bool STATS, int NF>
__device__ __forceinline__ void gemm_epilogue(f32x4* acc, const float* bias,
                                              void* outv, int N, int row0,
                                              int lane, float* sums) {
    __shared__ float ssum[NC];
    __shared__ float ssq[NC];
    if (STATS) {
        if (threadIdx.x < NC) { ssum[threadIdx.x] = 0.f; ssq[threadIdx.x] = 0.f; }
        __syncthreads();
    }
    const int col0 = lane & 15;
    const int crow = row0 + (lane >> 4) * 4;
#pragma unroll
    for (int f = 0; f < NF; ++f) {
        const int c = f * 16 + col0;
        float bv = BIAS ? bias[c] : 0.f;
        float sv = 0.f, qv = 0.f;
#pragma unroll
        for (int j = 0; j < 4; ++j) {
            int rr = crow + j;
            if (rr < N) {
                float v = acc[f][j] + bv;
                if (OUT_BF16) ((ushort*)outv)[(size_t)rr * NC + c] = f2bf(v);
                else          ((float*)outv)[(size_t)rr * NC + c] = v;
                if (STATS) { sv += v; qv += v * v; }
            }
        }
        if (STATS) {
            sv += __shfl_xor(sv, 16); sv += __shfl_xor(sv, 32);
            qv += __shfl_xor(qv, 16); qv += __shfl_xor(qv, 32);
            if ((lane >> 4) == 0) {
                atomicAdd(&ssum[c], sv);
                atomicAdd(&ssq[c], qv);
            }
        }
    }
    if (STATS) {
        __syncthreads();
        if (threadIdx.x < NC) {
            float* sh = sums + (blockIdx.x & (NSHARD - 1)) * 2 * NC;
            atomicAdd(&sh[threadIdx.x], ssum[threadIdx.x]);
            atomicAdd(&sh[NC + threadIdx.x], ssq[threadIdx.x]);
        }
    }
}

// MFMA GEMM, bf16 A: out[N,NC] = A[N,K] @ WT[NC,K]^T (+bias) [+col stats]
template <int K, int NC, bool BIAS, bool OUT_BF16, bool STATS>
__global__ __launch_bounds__(256) void gemm_mfma_k(const ushort* __restrict__ A,
                                                   const ushort* __restrict__ WT,
                                                   const float* __restrict__ bias,
                                                   void* __restrict__ outv, int N,
                                                   float* __restrict__ sums) {
    constexpr int NF = NC / 16;
    const int lane = threadIdx.x & 63;
    const int wave = threadIdx.x >> 6;
    const int row0 = blockIdx.x * 64 + wave * 16;
    const int col = lane & 15;
    const int k0 = (lane >> 4) * 8;
    int arow = row0 + col;
    if (arow >= N) arow = N - 1;

    f32x4 acc[NF];
#pragma unroll
    for (int f = 0; f < NF; ++f) acc[f] = (f32x4){0.f, 0.f, 0.f, 0.f};
#pragma unroll
    for (int kc = 0; kc < K; kc += 32) {
        bf16x8 af = *(const bf16x8*)&A[(size_t)arow * K + kc + k0];
#pragma unroll
        for (int f = 0; f < NF; ++f) {
            bf16x8 bf = *(const bf16x8*)&WT[(size_t)(f * 16 + col) * K + kc + k0];
            acc[f] = __builtin_amdgcn_mfma_f32_16x16x32_bf16(af, bf, acc[f], 0, 0, 0);
        }
    }
    gemm_epilogue<NC, BIAS, OUT_BF16, STATS, NF>(acc, bias, outv, N, row0, lane, sums);
}

// MFMA GEMM with fused BN finalize (from sharded sums) + BN-apply+ReLU on A
template <int K, int NC, bool OUT_BF16>
__global__ __launch_bounds__(256) void gemm_mfma_bnA_k(const ushort* __restrict__ U,
                                                       const ushort* __restrict__ WT,
                                                       const float* __restrict__ sums,
                                                       const float* __restrict__ g,
                                                       const float* __restrict__ be,
                                                       int Nbn,
                                                       void* __restrict__ outv, int N) {
    constexpr int NF = NC / 16;
    __shared__ __align__(16) float lsc[K];
    __shared__ __align__(16) float lsh[K];
    const int tid = threadIdx.x;
    if (tid < K) {
        float s = 0.f, q = 0.f;
#pragma unroll
        for (int sh = 0; sh < NSHARD; ++sh) {
            s += sums[sh * 2 * K + tid];
            q += sums[sh * 2 * K + K + tid];
        }
        float inv_n = 1.f / (float)Nbn;
        float mean = s * inv_n;
        float var = q * inv_n - mean * mean;
        float sc = g[tid] * rsqrtf(var + BN_EPS);
        lsc[tid] = sc;
        lsh[tid] = be[tid] - mean * sc;
    }
    __syncthreads();

    const int lane = tid & 63;
    const int wave = tid >> 6;
    const int row0 = blockIdx.x * 64 + wave * 16;
    const int col = lane & 15;
    const int k0 = (lane >> 4) * 8;
    int arow = row0 + col;
    if (arow >= N) arow = N - 1;

    f32x4 acc[NF];
#pragma unroll
    for (int f = 0; f < NF; ++f) acc[f] = (f32x4){0.f, 0.f, 0.f, 0.f};
#pragma unroll
    for (int kc = 0; kc < K; kc += 32) {
        bf16x8 raw = *(const bf16x8*)&U[(size_t)arow * K + kc + k0];
        float4 c0 = *(const float4*)&lsc[kc + k0];
        float4 c1 = *(const float4*)&lsc[kc + k0 + 4];
        float4 h0 = *(const float4*)&lsh[kc + k0];
        float4 h1 = *(const float4*)&lsh[kc + k0 + 4];
        bf16x8 af;
        af[0] = (short)f2bf(fmaxf(bf2f((ushort)raw[0]) * c0.x + h0.x, 0.f));
        af[1] = (short)f2bf(fmaxf(bf2f((ushort)raw[1]) * c0.y + h0.y, 0.f));
        af[2] = (short)f2bf(fmaxf(bf2f((ushort)raw[2]) * c0.z + h0.z, 0.f));
        af[3] = (short)f2bf(fmaxf(bf2f((ushort)raw[3]) * c0.w + h0.w, 0.f));
        af[4] = (short)f2bf(fmaxf(bf2f((ushort)raw[4]) * c1.x + h1.x, 0.f));
        af[5] = (short)f2bf(fmaxf(bf2f((ushort)raw[5]) * c1.y + h1.y, 0.f));
        af[6] = (short)f2bf(fmaxf(bf2f((ushort)raw[6]) * c1.z + h1.z, 0.f));
        af[7] = (short)f2bf(fmaxf(bf2f((ushort)raw[7]) * c1.w + h1.w, 0.f));
#pragma unroll
        for (int f = 0; f < NF; ++f) {
            bf16x8 bf = *(const bf16x8*)&WT[(size_t)(f * 16 + col) * K + kc + k0];
            acc[f] = __builtin_amdgcn_mfma_f32_16x16x32_bf16(af, bf, acc[f], 0, 0, 0);
        }
    }
    gemm_epilogue<NC, false, OUT_BF16, false, NF>(acc, nullptr, outv, N, row0, lane, nullptr);
}

// ---------------------------------------------------------------------------
// fused aggregation on bf16 rows: out = relu(T[i] + sum_j T[j] + bias)
// ---------------------------------------------------------------------------
__global__ void agg_f128b_k(const ushort* __restrict__ T, const int* __restrict__ row_start,
                            const int* __restrict__ esrc, const float* __restrict__ bias,
                            ushort* __restrict__ out, int N) {
    const int hw = (blockIdx.x << 3) | (threadIdx.x >> 5);
    const int lane = threadIdx.x & 31;
    if (hw >= N) return;
    const uint2* T2 = (const uint2*)T;
    uint2 sv = T2[(size_t)hw * 32 + lane];
    float a0, a1, a2, a3;
    unpack2(sv.x, a0, a1);
    unpack2(sv.y, a2, a3);
    int p = row_start[hw];
    const int pe = row_start[hw + 1];
    for (; p + 3 < pe; p += 4) {
        int s0 = esrc[p], s1 = esrc[p + 1], s2 = esrc[p + 2], s3 = esrc[p + 3];
        uint2 v0 = T2[(size_t)s0 * 32 + lane];
        uint2 v1 = T2[(size_t)s1 * 32 + lane];
        uint2 v2 = T2[(size_t)s2 * 32 + lane];
        uint2 v3 = T2[(size_t)s3 * 32 + lane];
        float x0, x1, x2, x3;
        unpack2(v0.x, x0, x1); unpack2(v0.y, x2, x3);
        a0 += x0; a1 += x1; a2 += x2; a3 += x3;
        unpack2(v1.x, x0, x1); unpack2(v1.y, x2, x3);
        a0 += x0; a1 += x1; a2 += x2; a3 += x3;
        unpack2(v2.x, x0, x1); unpack2(v2.y, x2, x3);
        a0 += x0; a1 += x1; a2 += x2; a3 += x3;
        unpack2(v3.x, x0, x1); unpack2(v3.y, x2, x3);
        a0 += x0; a1 += x1; a2 += x2; a3 += x3;
    }
    for (; p < pe; ++p) {
        uint2 v = T2[(size_t)esrc[p] * 32 + lane];
        float x0, x1, x2, x3;
        unpack2(v.x, x0, x1); unpack2(v.y, x2, x3);
        a0 += x0; a1 += x1; a2 += x2; a3 += x3;
    }
    const float4 b = ((const float4*)bias)[lane];
    a0 = fmaxf(a0 + b.x, 0.f);
    a1 = fmaxf(a1 + b.y, 0.f);
    a2 = fmaxf(a2 + b.z, 0.f);
    a3 = fmaxf(a3 + b.w, 0.f);
    ((uint2*)out)[(size_t)hw * 32 + lane] = make_uint2(pack2(a0, a1), pack2(a2, a3));
}

__global__ void agg_f32b_k(const ushort* __restrict__ T, const int* __restrict__ row_start,
                           const int* __restrict__ esrc, const float* __restrict__ bias,
                           ushort* __restrict__ out, int N) {
    const int wid = (blockIdx.x << 2) | (threadIdx.x >> 6);
    const int lane = threadIdx.x & 63;
    const int g = lane >> 3, l8 = lane & 7;
    if (wid >= N) return;
    const uint2* T2 = (const uint2*)T;
    float a0 = 0.f, a1 = 0.f, a2 = 0.f, a3 = 0.f;
    const int p0 = row_start[wid];
    const int pe = row_start[wid + 1];
    for (int p = p0 + g; p < pe; p += 8) {
        uint2 v = T2[(size_t)esrc[p] * 8 + l8];
        float x0, x1, x2, x3;
        unpack2(v.x, x0, x1); unpack2(v.y, x2, x3);
        a0 += x0; a1 += x1; a2 += x2; a3 += x3;
    }
#pragma unroll
    for (int off = 8; off < 64; off <<= 1) {
        a0 += __shfl_xor(a0, off);
        a1 += __shfl_xor(a1, off);
        a2 += __shfl_xor(a2, off);
        a3 += __shfl_xor(a3, off);
    }
    if (g == 0) {
        uint2 sv = T2[(size_t)wid * 8 + l8];
        float s0, s1, s2, s3;
        unpack2(sv.x, s0, s1); unpack2(sv.y, s2, s3);
        const float4 b = ((const float4*)bias)[l8];
        a0 = fmaxf(a0 + s0 + b.x, 0.f);
        a1 = fmaxf(a1 + s1 + b.y, 0.f);
        a2 = fmaxf(a2 + s2 + b.z, 0.f);
        a3 = fmaxf(a3 + s3 + b.w, 0.f);
        ((uint2*)out)[(size_t)wid * 8 + l8] = make_uint2(pack2(a0, a1), pack2(a2, a3));
    }
}

// ---------------------------------------------------------------------------
// bnapply with fused finalize (from sharded sums): f32 in -> f32 out
// ---------------------------------------------------------------------------
template <int F>
__global__ void bnapply_fin_k(const float* __restrict__ U, const float* __restrict__ sums,
                              const float* __restrict__ g, const float* __restrict__ be,
                              int Nbn, float* __restrict__ out, int total4) {
    __shared__ __align__(16) float lsc[F];
    __shared__ __align__(16) float lsh[F];
    const int tid = threadIdx.x;
    if (tid < F) {
        float s = 0.f, q = 0.f;
#pragma unroll
        for (int sh = 0; sh < NSHARD; ++sh) {
            s += sums[sh * 2 * F + tid];
            q += sums[sh * 2 * F + F + tid];
        }
        float inv_n = 1.f / (float)Nbn;
        float mean = s * inv_n;
        float var = q * inv_n - mean * mean;
        float sc = g[tid] * rsqrtf(var + BN_EPS);
        lsc[tid] = sc;
        lsh[tid] = be[tid] - mean * sc;
    }
    __syncthreads();
    const float4* U4 = (const float4*)U;
    float4* O4 = (float4*)out;
    const int stride = gridDim.x * blockDim.x;
    for (int i = blockIdx.x * blockDim.x + tid; i < total4; i += stride) {
        int c4 = (i % (F / 4)) * 4;
        float4 u = U4[i];
        float4 sc = *(const float4*)&lsc[c4];
        float4 sh = *(const float4*)&lsh[c4];
        float4 o;
        o.x = fmaxf(u.x * sc.x + sh.x, 0.f);
        o.y = fmaxf(u.y * sc.y + sh.y, 0.f);
        o.z = fmaxf(u.z * sc.z + sh.z, 0.f);
        o.w = fmaxf(u.w * sc.w + sh.w, 0.f);
        O4[i] = o;
    }
}

// ---------------------------------------------------------------------------
extern "C" void kernel_launch(void* const* d_in, const int* in_sizes, int n_in,
                              void* d_out, int out_size, void* d_ws, size_t ws_size,
                              hipStream_t stream) {
    const float* x   = (const float*)d_in[0];
    const int*   eb  = (const int*)d_in[1];
    const float* W1a = (const float*)d_in[2];
    const float* b1a = (const float*)d_in[3];
    const float* W1b = (const float*)d_in[4];
    const float* b1b = (const float*)d_in[5];
    const float* g1  = (const float*)d_in[6];
    const float* be1 = (const float*)d_in[7];
    const float* W2a = (const float*)d_in[8];
    const float* b2a = (const float*)d_in[9];
    const float* W2b = (const float*)d_in[10];
    const float* b2b = (const float*)d_in[11];
    const float* g2  = (const float*)d_in[12];
    const float* be2 = (const float*)d_in[13];
    float* out = (float*)d_out;

    const int N = in_sizes[0] / F_IN;  // 100000
    const int E = in_sizes[1] / 2;     // 3200000
    const int NBUCK = (N + 255) >> BSHIFT;  // 391

    char* w = (char*)d_ws;
    size_t off = 0;
    auto alloc = [&](size_t bytes) -> void* {
        void* p = w + off;
        off = (off + bytes + 255) & ~(size_t)255;
        return p;
    };
    ushort* B0 = (ushort*)alloc((size_t)N * H1 * 2);  // s1b -> s2b
    ushort* B1 = (ushort*)alloc((size_t)N * H1 * 2);  // t1b -> t2b
    char*   B2 = (char*)alloc((size_t)N * H1 * 4);    // u1b (bf16) -> u2 (f32)
    ushort* u1b = (ushort*)B2;
    float*  u2  = (float*)B2;

    int* row_start = (int*)alloc((size_t)(N + 1) * 4);
    int* esrc      = (int*)alloc((size_t)E * 4);
    uint* rec      = (uint*)alloc((size_t)NBUCK * BCAP * 4);
    int* bucket_cursor = (int*)alloc(512 * 4);
    ushort* w1aT = (ushort*)alloc(F_IN * H1 * 2);
    ushort* w1bT = (ushort*)alloc(H1 * H1 * 2);
    ushort* w2aT = (ushort*)alloc(H1 * H2 * 2);
    ushort* w2bT = (ushort*)alloc(H2 * H2 * 2);
    float* sums1 = (float*)alloc(NSHARD * 2 * H1 * 4);
    float* sums2 = (float*)alloc(NSHARD * 2 * H2 * 4);

    const int GB = (E + CHUNK - 1) / CHUNK;     // 1563 binA blocks
    const int G1 = (N + 63) / 64;               // 1563 gemm blocks

    // K0: weight casts + scratch zeroing
    super0_k<<<213, 256, 0, stream>>>(W1a, W1b, W2a, W2b, w1aT, w1bT, w2aT, w2bT,
                                      bucket_cursor, sums1, sums2);
    // K1: binA (CSR phase A) overlapped with gemm1 (t1 = x @ W1a)
    super1_k<<<GB + G1, 256, 0, stream>>>(eb, E, N, NBUCK, GB, bucket_cursor, rec,
                                          x, w1aT, B1);
    // K2: CSR phase B (prefix folded in)
    binB_k<<<NBUCK, 256, 0, stream>>>(rec, bucket_cursor, N, NBUCK, row_start, esrc);
    // K3: s1 = relu(t1 + agg(t1) + b1a)
    agg_f128b_k<<<(N + 7) / 8, 256, 0, stream>>>(B1, row_start, esrc, b1a, B0, N);
    // K4: u1 = s1 @ W1b + b1b (bf16 out) + fused column stats
    gemm_mfma_k<H1, H1, true, true, true><<<G1, 256, 0, stream>>>(B0, w1bT, b1b, u1b, N, sums1);
    // K5: t2 = relu(BN(u1)) @ W2a  (finalize + BN-apply fused into A-load)
    gemm_mfma_bnA_k<H1, H2, true><<<G1, 256, 0, stream>>>(u1b, w2aT, sums1, g1, be1, N, B1, N);
    // K6: s2 = relu(t2 + agg(t2) + b2a)
    agg_f32b_k<<<(N + 3) / 4, 256, 0, stream>>>(B1, row_start, esrc, b2a, B0, N);
    // K7: u2 = s2 @ W2b + b2b (f32 out) + fused column stats
    gemm_mfma_k<H2, H2, true, false, true><<<G1, 256, 0, stream>>>(B0, w2bT, b2b, u2, N, sums2);
    // K8: out = relu(BN(u2))  (finalize fused)
    bnapply_fin_k<H2><<<3125, 256, 0, stream>>>(u2, sums2, g2, be2, N, out, N * H2 / 4);
}